// Round 4
// baseline (428.633 us; speedup 1.0000x reference)
//
#include <hip/hip_runtime.h>

#define NODE_F 128
#define ENT_F  256
#define LDO    768   // out row stride: ENT_F * (DEPTH+1)
#define NEG_INF -3.4e38f

__device__ __forceinline__ unsigned short f2bf(float x) {
    unsigned u = __float_as_uint(x);
    u += 0x7FFFu + ((u >> 16) & 1u);          // round-to-nearest-even
    return (unsigned short)(u >> 16);
}
__device__ __forceinline__ float bf2f(unsigned short h) {
    return __uint_as_float(((unsigned)h) << 16);
}

// ================= CSR build (blockIdx.y = graph: 0=adj,1=ent,2=rel) =================

__global__ void count3_k(const int* __restrict__ r0, const int* __restrict__ r1,
                         const int* __restrict__ r2, int E0, int E1, int E2,
                         int* __restrict__ deg3, int N) {
    int i = blockIdx.x * blockDim.x + threadIdx.x;
    int y = blockIdx.y;
    const int* rp = (y == 0) ? r0 : (y == 1) ? r1 : r2;
    int Eg = (y == 0) ? E0 : (y == 1) ? E1 : E2;
    if (i < Eg) atomicAdd(&deg3[(size_t)y * N + rp[i]], 1);
}

// ticket allocator: per-wave inclusive scan of degrees + one atomicAdd per wave.
// Produces start3 (row base) and cur3 (scatter cursor). Row ranges are disjoint
// and contiguous but NOT monotone across rows — consumers use start3+deg3 only.
__global__ void alloc3_k(const int* __restrict__ deg3, int* __restrict__ tot3,
                         int* __restrict__ start3, int* __restrict__ cur3, int N) {
    int y = blockIdx.y;
    int i = blockIdx.x * blockDim.x + threadIdx.x;
    int lane = threadIdx.x & 63;
    int d = (i < N) ? deg3[(size_t)y * N + i] : 0;
    int v = d;
    #pragma unroll
    for (int o = 1; o < 64; o <<= 1) {
        int t = __shfl_up(v, o);
        if (lane >= o) v += t;
    }
    int wsum = __shfl(v, 63);
    int base = 0;
    if (lane == 63) base = atomicAdd(&tot3[y], wsum);
    base = __shfl(base, 63);
    if (i < N) {
        int st = base + v - d;
        start3[(size_t)y * N + i] = st;
        cur3[(size_t)y * N + i] = st;
    }
}

__global__ void scatter3_k(const int* __restrict__ r0, const int* __restrict__ c0,
                           const int* __restrict__ r1, const int* __restrict__ c1,
                           const int* __restrict__ r2, const int* __restrict__ c2,
                           int E0, int E1, int E2, int* __restrict__ cur3,
                           int* __restrict__ col_adj, int* __restrict__ eid_adj,
                           int* __restrict__ col_ent, int* __restrict__ col_rel,
                           const float* __restrict__ rel_attn, float* __restrict__ rel_attn_s,
                           int N) {
    int e = blockIdx.x * blockDim.x + threadIdx.x;
    int y = blockIdx.y;
    const int* rp = (y == 0) ? r0 : (y == 1) ? r1 : r2;
    const int* cp = (y == 0) ? c0 : (y == 1) ? c1 : c2;
    int* colp = (y == 0) ? col_adj : (y == 1) ? col_ent : col_rel;
    int Eg = (y == 0) ? E0 : (y == 1) ? E1 : E2;
    if (e >= Eg) return;
    int r = rp[e];
    int pos = atomicAdd(&cur3[(size_t)y * N + r], 1);
    colp[pos] = cp[e];
    if (y == 0) {
        eid_adj[pos] = e;
        rel_attn_s[pos] = rel_attn[e];   // pre-permute into sorted order
    }
}

// ================= small map kernels =================

__global__ void rel_proj_k(const float* __restrict__ rel_emb, const float* __restrict__ a_rel,
                           float* __restrict__ proj, int R) {
    int r = blockIdx.x * blockDim.x + threadIdx.x;
    if (r >= R) return;
    float s = 0.0f;
    #pragma unroll 4
    for (int f = 0; f < NODE_F; ++f) s += rel_emb[(size_t)r * NODE_F + f] * a_rel[f];
    proj[r] = s;
}

// sp_row is a bijection (arange) -> plain store
__global__ void rel_attn_map_k(const float* __restrict__ sp_val, const int* __restrict__ sp_row,
                               const int* __restrict__ sp_col, const float* __restrict__ proj,
                               float* __restrict__ rel_attn, int E) {
    int e = blockIdx.x * blockDim.x + threadIdx.x;
    if (e < E) rel_attn[sp_row[e]] = sp_val[e] * proj[sp_col[e]];
}

// ================= fused feature kernels =================

// one wave per node: ent-mean (cols 0..127) + rel-mean (cols 128..255), relu,
// write f32 out (+ optional bf16 mirror), and a_s/a_n dots from in-register feats.
__global__ void meanagg_fused_k(const int* __restrict__ st_ent, const int* __restrict__ dg_ent,
                                const int* __restrict__ col_ent,
                                const int* __restrict__ st_rel, const int* __restrict__ dg_rel,
                                const int* __restrict__ col_rel,
                                const float* __restrict__ ent_emb, const float* __restrict__ rel_emb,
                                const float* __restrict__ a_self, const float* __restrict__ a_neigh,
                                float* __restrict__ out, unsigned short* __restrict__ fb0,
                                float* __restrict__ a_s_out, float* __restrict__ a_n_out, int N) {
    int n = blockIdx.x * (blockDim.x >> 6) + (threadIdx.x >> 6);
    int lane = threadIdx.x & 63;
    if (n >= N) return;

    int s = st_ent[n], deg = dg_ent[n];
    float2 ea = {0.0f, 0.0f};
    for (int p = s; p < s + deg; ++p) {
        float2 v = reinterpret_cast<const float2*>(&ent_emb[(size_t)col_ent[p] * NODE_F])[lane];
        ea.x += v.x; ea.y += v.y;
    }
    if (deg > 0) { float w = 1.0f / (float)deg; ea.x *= w; ea.y *= w; }

    s = st_rel[n]; deg = dg_rel[n];
    float2 ra = {0.0f, 0.0f};
    for (int p = s; p < s + deg; ++p) {
        float2 v = reinterpret_cast<const float2*>(&rel_emb[(size_t)col_rel[p] * NODE_F])[lane];
        ra.x += v.x; ra.y += v.y;
    }
    if (deg > 0) { float w = 1.0f / (float)deg; ra.x *= w; ra.y *= w; }

    ea.x = ea.x > 0.0f ? ea.x : 0.0f;  ea.y = ea.y > 0.0f ? ea.y : 0.0f;
    ra.x = ra.x > 0.0f ? ra.x : 0.0f;  ra.y = ra.y > 0.0f ? ra.y : 0.0f;

    reinterpret_cast<float2*>(&out[(size_t)n * LDO])[lane] = ea;
    reinterpret_cast<float2*>(&out[(size_t)n * LDO + NODE_F])[lane] = ra;
    if (fb0) {
        ushort2 eb; eb.x = f2bf(ea.x); eb.y = f2bf(ea.y);
        ushort2 rb; rb.x = f2bf(ra.x); rb.y = f2bf(ra.y);
        reinterpret_cast<ushort2*>(&fb0[(size_t)n * ENT_F])[lane] = eb;
        reinterpret_cast<ushort2*>(&fb0[(size_t)n * ENT_F + NODE_F])[lane] = rb;
    }

    float2 se = reinterpret_cast<const float2*>(a_self)[lane];
    float2 sr = reinterpret_cast<const float2*>(a_self)[64 + lane];
    float2 ne = reinterpret_cast<const float2*>(a_neigh)[lane];
    float2 nr = reinterpret_cast<const float2*>(a_neigh)[64 + lane];
    float ds = ea.x * se.x + ea.y * se.y + ra.x * sr.x + ra.y * sr.y;
    float dn = ea.x * ne.x + ea.y * ne.y + ra.x * nr.x + ra.y * nr.y;
    #pragma unroll
    for (int o = 32; o > 0; o >>= 1) {
        ds += __shfl_xor(ds, o);
        dn += __shfl_xor(dn, o);
    }
    if (lane == 0) { a_s_out[n] = ds; a_n_out[n] = dn; }
}

// one wave per node: fused softmax (lane-per-edge) + weighted gather + relu
// + optional next-depth a_s/a_n + optional bf16 mirror write + optional att scatter.
__global__ void attn_agg_fused_k(const int* __restrict__ st, const int* __restrict__ dg,
                                 const int* __restrict__ col_s, const int* __restrict__ eid_s,
                                 const float* __restrict__ rel_attn_s,
                                 const float* __restrict__ a_s_in, const float* __restrict__ a_n_in,
                                 const float* __restrict__ a_self, const float* __restrict__ a_neigh,
                                 float* __restrict__ a_s_out, float* __restrict__ a_n_out,
                                 float* __restrict__ out, int src, int dst,
                                 const unsigned short* __restrict__ fb_src,
                                 unsigned short* __restrict__ fb_dst,
                                 float* __restrict__ att_out, int N) {
    int n = blockIdx.x * (blockDim.x >> 6) + (threadIdx.x >> 6);
    int lane = threadIdx.x & 63;
    if (n >= N) return;
    int s = st[n];
    int deg = dg[n];
    float4 acc = {0.0f, 0.0f, 0.0f, 0.0f};

    if (deg > 0) {
        float as_row = a_s_in[n];
        if (deg <= 64) {
            float myv = NEG_INF;
            int mycol = 0;
            if (lane < deg) {
                int p = s + lane;
                mycol = col_s[p];
                float v = rel_attn_s[p] + as_row + a_n_in[mycol];
                myv = v >= 0.0f ? v : 0.2f * v;
            }
            float m = myv;
            #pragma unroll
            for (int o = 32; o > 0; o >>= 1) {
                float x = __shfl_xor(m, o);
                m = x > m ? x : m;
            }
            float ex = (lane < deg) ? __expf(myv - m) : 0.0f;
            float ssum = ex;
            #pragma unroll
            for (int o = 32; o > 0; o >>= 1) ssum += __shfl_xor(ssum, o);
            float myatt = ex / ssum;
            if (att_out && lane < deg) att_out[eid_s[s + lane]] = myatt;
            if (fb_src) {
                for (int p = 0; p < deg; ++p) {
                    float a = __shfl(myatt, p);
                    int c = __shfl(mycol, p);
                    ushort4 v = reinterpret_cast<const ushort4*>(&fb_src[(size_t)c * ENT_F])[lane];
                    acc.x += a * bf2f(v.x); acc.y += a * bf2f(v.y);
                    acc.z += a * bf2f(v.z); acc.w += a * bf2f(v.w);
                }
            } else {
                for (int p = 0; p < deg; ++p) {
                    float a = __shfl(myatt, p);
                    int c = __shfl(mycol, p);
                    float4 v = reinterpret_cast<const float4*>(&out[(size_t)c * LDO + src])[lane];
                    acc.x += a * v.x; acc.y += a * v.y; acc.z += a * v.z; acc.w += a * v.w;
                }
            }
        } else {  // rare fallback: deg > 64
            float m = NEG_INF;
            for (int p = s + lane; p < s + deg; p += 64) {
                float v = rel_attn_s[p] + as_row + a_n_in[col_s[p]];
                v = v >= 0.0f ? v : 0.2f * v;
                m = v > m ? v : m;
            }
            #pragma unroll
            for (int o = 32; o > 0; o >>= 1) {
                float x = __shfl_xor(m, o);
                m = x > m ? x : m;
            }
            float ssum = 0.0f;
            for (int p = s + lane; p < s + deg; p += 64) {
                float v = rel_attn_s[p] + as_row + a_n_in[col_s[p]];
                v = v >= 0.0f ? v : 0.2f * v;
                ssum += __expf(v - m);
            }
            #pragma unroll
            for (int o = 32; o > 0; o >>= 1) ssum += __shfl_xor(ssum, o);
            float inv = 1.0f / ssum;
            for (int p = s; p < s + deg; ++p) {
                int c = col_s[p];
                float v = rel_attn_s[p] + as_row + a_n_in[c];
                v = v >= 0.0f ? v : 0.2f * v;
                float a = __expf(v - m) * inv;
                if (att_out && lane == 0) att_out[eid_s[p]] = a;
                float4 fv = reinterpret_cast<const float4*>(&out[(size_t)c * LDO + src])[lane];
                acc.x += a * fv.x; acc.y += a * fv.y; acc.z += a * fv.z; acc.w += a * fv.w;
            }
        }
    }

    acc.x = acc.x > 0.0f ? acc.x : 0.0f;
    acc.y = acc.y > 0.0f ? acc.y : 0.0f;
    acc.z = acc.z > 0.0f ? acc.z : 0.0f;
    acc.w = acc.w > 0.0f ? acc.w : 0.0f;
    reinterpret_cast<float4*>(&out[(size_t)n * LDO + dst])[lane] = acc;
    if (fb_dst) {
        ushort4 b;
        b.x = f2bf(acc.x); b.y = f2bf(acc.y); b.z = f2bf(acc.z); b.w = f2bf(acc.w);
        reinterpret_cast<ushort4*>(&fb_dst[(size_t)n * ENT_F])[lane] = b;
    }

    if (a_s_out) {
        float4 s4 = reinterpret_cast<const float4*>(a_self)[lane];
        float4 n4 = reinterpret_cast<const float4*>(a_neigh)[lane];
        float ds = acc.x * s4.x + acc.y * s4.y + acc.z * s4.z + acc.w * s4.w;
        float dn = acc.x * n4.x + acc.y * n4.y + acc.z * n4.z + acc.w * n4.w;
        #pragma unroll
        for (int o = 32; o > 0; o >>= 1) {
            ds += __shfl_xor(ds, o);
            dn += __shfl_xor(dn, o);
        }
        if (lane == 0) { a_s_out[n] = ds; a_n_out[n] = dn; }
    }
}

// ================= launch =================

extern "C" void kernel_launch(void* const* d_in, const int* in_sizes, int n_in,
                              void* d_out, int out_size, void* d_ws, size_t ws_size,
                              hipStream_t stream) {
    const float* ent_emb = (const float*)d_in[0];
    const float* rel_emb = (const float*)d_in[1];
    const float* a_self  = (const float*)d_in[2];
    const float* a_neigh = (const float*)d_in[3];
    const float* a_rel   = (const float*)d_in[4];
    const float* sp_val  = (const float*)d_in[5];
    const int*   adj_row = (const int*)d_in[6];
    const int*   adj_col = (const int*)d_in[7];
    const int*   sp_row  = (const int*)d_in[8];
    const int*   sp_col  = (const int*)d_in[9];
    const int*   rel_row = (const int*)d_in[10];
    const int*   rel_col = (const int*)d_in[11];
    const int*   ent_row = (const int*)d_in[12];
    const int*   ent_col = (const int*)d_in[13];

    const int N  = in_sizes[0] / NODE_F;
    const int R  = in_sizes[1] / NODE_F;
    const int E  = in_sizes[5];
    const int ER = in_sizes[10];
    const int EE = in_sizes[12];

    float* out = (float*)d_out;
    float* att_out = out + (size_t)N * LDO;

    const int TB = 256;
    int maxE = E > EE ? E : EE; if (ER > maxE) maxE = ER;

    // ---- workspace ----
    char* w0 = (char*)d_ws;
    char* w = w0;
    int* deg3    = (int*)w;  w += (size_t)3 * N * 4;
    int* tot3    = (int*)w;  w += 4 * 4;                 // 3 counters (+pad), memset with deg3
    int* start3  = (int*)w;  w += (size_t)3 * N * 4;
    int* cur3    = (int*)w;  w += (size_t)3 * N * 4;
    int* col_adj = (int*)w;  w += (size_t)E * 4;
    int* eid_adj = (int*)w;  w += (size_t)E * 4;
    int* col_ent = (int*)w;  w += (size_t)EE * 4;
    int* col_rel = (int*)w;  w += (size_t)ER * 4;
    float* rel_attn   = (float*)w;  w += (size_t)E * 4;
    float* rel_attn_s = (float*)w;  w += (size_t)E * 4;
    float* proj       = (float*)w;  w += (size_t)R * 4;
    float* a_s0       = (float*)w;  w += (size_t)N * 4;
    float* a_n0       = (float*)w;  w += (size_t)N * 4;
    float* a_s1       = (float*)w;  w += (size_t)N * 4;
    float* a_n1       = (float*)w;  w += (size_t)N * 4;

    // optional bf16 feature mirrors (slice0, slice1), gated on ws_size
    w = (char*)(((size_t)w + 15) & ~(size_t)15);
    size_t slice_bytes = (size_t)N * ENT_F * 2;
    unsigned short* fb0 = nullptr;
    unsigned short* fb1 = nullptr;
    if ((size_t)(w - w0) + 2 * slice_bytes <= ws_size) {
        fb0 = (unsigned short*)w;
        fb1 = (unsigned short*)(w + slice_bytes);
    }

    int* st_adj = start3;          int* dg_adj = deg3;
    int* st_ent = start3 + N;      int* dg_ent = deg3 + N;
    int* st_rel = start3 + 2 * N;  int* dg_rel = deg3 + 2 * N;

    // ---- relation attention term (independent; needed by scatter3) ----
    rel_proj_k<<<(R + TB - 1) / TB, TB, 0, stream>>>(rel_emb, a_rel, proj, R);
    rel_attn_map_k<<<(E + TB - 1) / TB, TB, 0, stream>>>(sp_val, sp_row, sp_col, proj, rel_attn, E);

    // ---- CSR build: count -> ticket-alloc -> scatter ----
    hipMemsetAsync(deg3, 0, ((size_t)3 * N + 4) * sizeof(int), stream);  // deg3 + tot3
    {
        dim3 g((maxE + TB - 1) / TB, 3);
        count3_k<<<g, TB, 0, stream>>>(adj_row, ent_row, rel_row, E, EE, ER, deg3, N);
    }
    {
        dim3 g((N + TB - 1) / TB, 3);
        alloc3_k<<<g, TB, 0, stream>>>(deg3, tot3, start3, cur3, N);
    }
    {
        dim3 g((maxE + TB - 1) / TB, 3);
        scatter3_k<<<g, TB, 0, stream>>>(adj_row, adj_col, ent_row, ent_col, rel_row, rel_col,
                                         E, EE, ER, cur3, col_adj, eid_adj, col_ent, col_rel,
                                         rel_attn, rel_attn_s, N);
    }

    // ---- initial features + depth-1 a_s/a_n ----
    meanagg_fused_k<<<(N + 3) / 4, 256, 0, stream>>>(st_ent, dg_ent, col_ent,
                                                     st_rel, dg_rel, col_rel,
                                                     ent_emb, rel_emb, a_self, a_neigh,
                                                     out, fb0, a_s0, a_n0, N);

    // ---- depth 1 ----
    attn_agg_fused_k<<<(N + 3) / 4, 256, 0, stream>>>(st_adj, dg_adj, col_adj, eid_adj,
                                                      rel_attn_s, a_s0, a_n0, a_self, a_neigh,
                                                      a_s1, a_n1, out, 0, ENT_F,
                                                      fb0, fb1, nullptr, N);

    // ---- depth 2 ----
    attn_agg_fused_k<<<(N + 3) / 4, 256, 0, stream>>>(st_adj, dg_adj, col_adj, eid_adj,
                                                      rel_attn_s, a_s1, a_n1, nullptr, nullptr,
                                                      nullptr, nullptr, out, ENT_F, 2 * ENT_F,
                                                      fb1, nullptr, att_out, N);
}

// Round 5
// 388.042 us; speedup vs baseline: 1.1046x; 1.1046x over previous
//
#include <hip/hip_runtime.h>

#define NODE_F 128
#define ENT_F  256
#define LDO    768   // out row stride: ENT_F * (DEPTH+1)
#define NEG_INF -3.4e38f

// ================= CSR build (blockIdx.y = graph: 0=adj,1=ent,2=rel) =================

__global__ void count3_k(const int* __restrict__ r0, const int* __restrict__ r1,
                         const int* __restrict__ r2, int E0, int E1, int E2,
                         int* __restrict__ deg3, int N) {
    int i = blockIdx.x * blockDim.x + threadIdx.x;
    int y = blockIdx.y;
    const int* rp = (y == 0) ? r0 : (y == 1) ? r1 : r2;
    int Eg = (y == 0) ? E0 : (y == 1) ? E1 : E2;
    if (i < Eg) atomicAdd(&deg3[(size_t)y * N + rp[i]], 1);
}

// ticket allocator: per-wave inclusive scan of degrees + one atomicAdd per wave.
__global__ void alloc3_k(const int* __restrict__ deg3, int* __restrict__ tot3,
                         int* __restrict__ start3, int* __restrict__ cur3, int N) {
    int y = blockIdx.y;
    int i = blockIdx.x * blockDim.x + threadIdx.x;
    int lane = threadIdx.x & 63;
    int d = (i < N) ? deg3[(size_t)y * N + i] : 0;
    int v = d;
    #pragma unroll
    for (int o = 1; o < 64; o <<= 1) {
        int t = __shfl_up(v, o);
        if (lane >= o) v += t;
    }
    int wsum = __shfl(v, 63);
    int base = 0;
    if (lane == 63) base = atomicAdd(&tot3[y], wsum);
    base = __shfl(base, 63);
    if (i < N) {
        int st = base + v - d;
        start3[(size_t)y * N + i] = st;
        cur3[(size_t)y * N + i] = st;
    }
}

// scatter + (for adj) fused rel_attn compute in sorted order:
// sp_row == arange(E), so rel_attn[e] = sp_val[e] * proj[sp_col[e]].
__global__ void scatter3_k(const int* __restrict__ r0, const int* __restrict__ c0,
                           const int* __restrict__ r1, const int* __restrict__ c1,
                           const int* __restrict__ r2, const int* __restrict__ c2,
                           int E0, int E1, int E2, int* __restrict__ cur3,
                           int* __restrict__ col_adj, int* __restrict__ eid_adj,
                           int* __restrict__ col_ent, int* __restrict__ col_rel,
                           const float* __restrict__ sp_val, const int* __restrict__ sp_col,
                           const float* __restrict__ proj, float* __restrict__ rel_attn_s,
                           int N) {
    int e = blockIdx.x * blockDim.x + threadIdx.x;
    int y = blockIdx.y;
    const int* rp = (y == 0) ? r0 : (y == 1) ? r1 : r2;
    const int* cp = (y == 0) ? c0 : (y == 1) ? c1 : c2;
    int* colp = (y == 0) ? col_adj : (y == 1) ? col_ent : col_rel;
    int Eg = (y == 0) ? E0 : (y == 1) ? E1 : E2;
    if (e >= Eg) return;
    int r = rp[e];
    int pos = atomicAdd(&cur3[(size_t)y * N + r], 1);
    colp[pos] = cp[e];
    if (y == 0) {
        eid_adj[pos] = e;
        rel_attn_s[pos] = sp_val[e] * proj[sp_col[e]];
    }
}

__global__ void rel_proj_k(const float* __restrict__ rel_emb, const float* __restrict__ a_rel,
                           float* __restrict__ proj, int R) {
    int r = blockIdx.x * blockDim.x + threadIdx.x;
    if (r >= R) return;
    float s = 0.0f;
    #pragma unroll 4
    for (int f = 0; f < NODE_F; ++f) s += rel_emb[(size_t)r * NODE_F + f] * a_rel[f];
    proj[r] = s;
}

// ================= fused feature kernels =================

// one wave per node: ent-mean (cols 0..127) + rel-mean (cols 128..255), relu,
// write out, a_s/a_n from in-register feats. 4-wide edge batching for MLP.
__global__ void meanagg_fused_k(const int* __restrict__ st_ent, const int* __restrict__ dg_ent,
                                const int* __restrict__ col_ent,
                                const int* __restrict__ st_rel, const int* __restrict__ dg_rel,
                                const int* __restrict__ col_rel,
                                const float* __restrict__ ent_emb, const float* __restrict__ rel_emb,
                                const float* __restrict__ a_self, const float* __restrict__ a_neigh,
                                float* __restrict__ out,
                                float* __restrict__ a_s_out, float* __restrict__ a_n_out, int N) {
    int n = blockIdx.x * (blockDim.x >> 6) + (threadIdx.x >> 6);
    int lane = threadIdx.x & 63;
    if (n >= N) return;

    float2 ea = {0.0f, 0.0f};
    {
        int s = st_ent[n], deg = dg_ent[n];
        int p = 0;
        for (; p + 4 <= deg; p += 4) {
            int c0 = col_ent[s + p], c1 = col_ent[s + p + 1];
            int c2 = col_ent[s + p + 2], c3 = col_ent[s + p + 3];
            float2 v0 = reinterpret_cast<const float2*>(&ent_emb[(size_t)c0 * NODE_F])[lane];
            float2 v1 = reinterpret_cast<const float2*>(&ent_emb[(size_t)c1 * NODE_F])[lane];
            float2 v2 = reinterpret_cast<const float2*>(&ent_emb[(size_t)c2 * NODE_F])[lane];
            float2 v3 = reinterpret_cast<const float2*>(&ent_emb[(size_t)c3 * NODE_F])[lane];
            ea.x += v0.x + v1.x + v2.x + v3.x;
            ea.y += v0.y + v1.y + v2.y + v3.y;
        }
        for (; p < deg; ++p) {
            float2 v = reinterpret_cast<const float2*>(&ent_emb[(size_t)col_ent[s + p] * NODE_F])[lane];
            ea.x += v.x; ea.y += v.y;
        }
        if (deg > 0) { float w = 1.0f / (float)deg; ea.x *= w; ea.y *= w; }
    }

    float2 ra = {0.0f, 0.0f};
    {
        int s = st_rel[n], deg = dg_rel[n];
        int p = 0;
        for (; p + 4 <= deg; p += 4) {
            int c0 = col_rel[s + p], c1 = col_rel[s + p + 1];
            int c2 = col_rel[s + p + 2], c3 = col_rel[s + p + 3];
            float2 v0 = reinterpret_cast<const float2*>(&rel_emb[(size_t)c0 * NODE_F])[lane];
            float2 v1 = reinterpret_cast<const float2*>(&rel_emb[(size_t)c1 * NODE_F])[lane];
            float2 v2 = reinterpret_cast<const float2*>(&rel_emb[(size_t)c2 * NODE_F])[lane];
            float2 v3 = reinterpret_cast<const float2*>(&rel_emb[(size_t)c3 * NODE_F])[lane];
            ra.x += v0.x + v1.x + v2.x + v3.x;
            ra.y += v0.y + v1.y + v2.y + v3.y;
        }
        for (; p < deg; ++p) {
            float2 v = reinterpret_cast<const float2*>(&rel_emb[(size_t)col_rel[s + p] * NODE_F])[lane];
            ra.x += v.x; ra.y += v.y;
        }
        if (deg > 0) { float w = 1.0f / (float)deg; ra.x *= w; ra.y *= w; }
    }

    ea.x = ea.x > 0.0f ? ea.x : 0.0f;  ea.y = ea.y > 0.0f ? ea.y : 0.0f;
    ra.x = ra.x > 0.0f ? ra.x : 0.0f;  ra.y = ra.y > 0.0f ? ra.y : 0.0f;

    reinterpret_cast<float2*>(&out[(size_t)n * LDO])[lane] = ea;
    reinterpret_cast<float2*>(&out[(size_t)n * LDO + NODE_F])[lane] = ra;

    float2 se = reinterpret_cast<const float2*>(a_self)[lane];
    float2 sr = reinterpret_cast<const float2*>(a_self)[64 + lane];
    float2 ne = reinterpret_cast<const float2*>(a_neigh)[lane];
    float2 nr = reinterpret_cast<const float2*>(a_neigh)[64 + lane];
    float ds = ea.x * se.x + ea.y * se.y + ra.x * sr.x + ra.y * sr.y;
    float dn = ea.x * ne.x + ea.y * ne.y + ra.x * nr.x + ra.y * nr.y;
    #pragma unroll
    for (int o = 32; o > 0; o >>= 1) {
        ds += __shfl_xor(ds, o);
        dn += __shfl_xor(dn, o);
    }
    if (lane == 0) { a_s_out[n] = ds; a_n_out[n] = dn; }
}

// one wave per node: fused softmax (lane-per-edge) + weighted gather (4-wide MLP)
// + relu + optional next-depth a_s/a_n + optional att scatter.
__global__ void attn_agg_fused_k(const int* __restrict__ st, const int* __restrict__ dg,
                                 const int* __restrict__ col_s, const int* __restrict__ eid_s,
                                 const float* __restrict__ rel_attn_s,
                                 const float* __restrict__ a_s_in, const float* __restrict__ a_n_in,
                                 const float* __restrict__ a_self, const float* __restrict__ a_neigh,
                                 float* __restrict__ a_s_out, float* __restrict__ a_n_out,
                                 float* __restrict__ out, int src, int dst,
                                 float* __restrict__ att_out, int N) {
    int n = blockIdx.x * (blockDim.x >> 6) + (threadIdx.x >> 6);
    int lane = threadIdx.x & 63;
    if (n >= N) return;
    int s = st[n];
    int deg = dg[n];
    float4 acc = {0.0f, 0.0f, 0.0f, 0.0f};

    if (deg > 0) {
        float as_row = a_s_in[n];
        if (deg <= 64) {
            float myv = NEG_INF;
            int mycol = 0;
            if (lane < deg) {
                int p = s + lane;
                mycol = col_s[p];
                float v = rel_attn_s[p] + as_row + a_n_in[mycol];
                myv = v >= 0.0f ? v : 0.2f * v;
            }
            float m = myv;
            #pragma unroll
            for (int o = 32; o > 0; o >>= 1) {
                float x = __shfl_xor(m, o);
                m = x > m ? x : m;
            }
            float ex = (lane < deg) ? __expf(myv - m) : 0.0f;
            float ssum = ex;
            #pragma unroll
            for (int o = 32; o > 0; o >>= 1) ssum += __shfl_xor(ssum, o);
            float myatt = ex / ssum;
            if (att_out && lane < deg) att_out[eid_s[s + lane]] = myatt;

            int p = 0;
            for (; p + 4 <= deg; p += 4) {
                float a0 = __shfl(myatt, p),     a1 = __shfl(myatt, p + 1);
                float a2 = __shfl(myatt, p + 2), a3 = __shfl(myatt, p + 3);
                int c0 = __shfl(mycol, p),     c1 = __shfl(mycol, p + 1);
                int c2 = __shfl(mycol, p + 2), c3 = __shfl(mycol, p + 3);
                float4 v0 = reinterpret_cast<const float4*>(&out[(size_t)c0 * LDO + src])[lane];
                float4 v1 = reinterpret_cast<const float4*>(&out[(size_t)c1 * LDO + src])[lane];
                float4 v2 = reinterpret_cast<const float4*>(&out[(size_t)c2 * LDO + src])[lane];
                float4 v3 = reinterpret_cast<const float4*>(&out[(size_t)c3 * LDO + src])[lane];
                acc.x += a0 * v0.x + a1 * v1.x + a2 * v2.x + a3 * v3.x;
                acc.y += a0 * v0.y + a1 * v1.y + a2 * v2.y + a3 * v3.y;
                acc.z += a0 * v0.z + a1 * v1.z + a2 * v2.z + a3 * v3.z;
                acc.w += a0 * v0.w + a1 * v1.w + a2 * v2.w + a3 * v3.w;
            }
            for (; p < deg; ++p) {
                float a = __shfl(myatt, p);
                int c = __shfl(mycol, p);
                float4 v = reinterpret_cast<const float4*>(&out[(size_t)c * LDO + src])[lane];
                acc.x += a * v.x; acc.y += a * v.y; acc.z += a * v.z; acc.w += a * v.w;
            }
        } else {  // rare fallback: deg > 64
            float m = NEG_INF;
            for (int p = s + lane; p < s + deg; p += 64) {
                float v = rel_attn_s[p] + as_row + a_n_in[col_s[p]];
                v = v >= 0.0f ? v : 0.2f * v;
                m = v > m ? v : m;
            }
            #pragma unroll
            for (int o = 32; o > 0; o >>= 1) {
                float x = __shfl_xor(m, o);
                m = x > m ? x : m;
            }
            float ssum = 0.0f;
            for (int p = s + lane; p < s + deg; p += 64) {
                float v = rel_attn_s[p] + as_row + a_n_in[col_s[p]];
                v = v >= 0.0f ? v : 0.2f * v;
                ssum += __expf(v - m);
            }
            #pragma unroll
            for (int o = 32; o > 0; o >>= 1) ssum += __shfl_xor(ssum, o);
            float inv = 1.0f / ssum;
            for (int p = s; p < s + deg; ++p) {
                int c = col_s[p];
                float v = rel_attn_s[p] + as_row + a_n_in[c];
                v = v >= 0.0f ? v : 0.2f * v;
                float a = __expf(v - m) * inv;
                if (att_out && lane == 0) att_out[eid_s[p]] = a;
                float4 fv = reinterpret_cast<const float4*>(&out[(size_t)c * LDO + src])[lane];
                acc.x += a * fv.x; acc.y += a * fv.y; acc.z += a * fv.z; acc.w += a * fv.w;
            }
        }
    }

    acc.x = acc.x > 0.0f ? acc.x : 0.0f;
    acc.y = acc.y > 0.0f ? acc.y : 0.0f;
    acc.z = acc.z > 0.0f ? acc.z : 0.0f;
    acc.w = acc.w > 0.0f ? acc.w : 0.0f;
    reinterpret_cast<float4*>(&out[(size_t)n * LDO + dst])[lane] = acc;

    if (a_s_out) {
        float4 s4 = reinterpret_cast<const float4*>(a_self)[lane];
        float4 n4 = reinterpret_cast<const float4*>(a_neigh)[lane];
        float ds = acc.x * s4.x + acc.y * s4.y + acc.z * s4.z + acc.w * s4.w;
        float dn = acc.x * n4.x + acc.y * n4.y + acc.z * n4.z + acc.w * n4.w;
        #pragma unroll
        for (int o = 32; o > 0; o >>= 1) {
            ds += __shfl_xor(ds, o);
            dn += __shfl_xor(dn, o);
        }
        if (lane == 0) { a_s_out[n] = ds; a_n_out[n] = dn; }
    }
}

// ================= launch =================

extern "C" void kernel_launch(void* const* d_in, const int* in_sizes, int n_in,
                              void* d_out, int out_size, void* d_ws, size_t ws_size,
                              hipStream_t stream) {
    const float* ent_emb = (const float*)d_in[0];
    const float* rel_emb = (const float*)d_in[1];
    const float* a_self  = (const float*)d_in[2];
    const float* a_neigh = (const float*)d_in[3];
    const float* a_rel   = (const float*)d_in[4];
    const float* sp_val  = (const float*)d_in[5];
    const int*   adj_row = (const int*)d_in[6];
    const int*   adj_col = (const int*)d_in[7];
    const int*   sp_col  = (const int*)d_in[9];
    const int*   rel_row = (const int*)d_in[10];
    const int*   rel_col = (const int*)d_in[11];
    const int*   ent_row = (const int*)d_in[12];
    const int*   ent_col = (const int*)d_in[13];

    const int N  = in_sizes[0] / NODE_F;
    const int R  = in_sizes[1] / NODE_F;
    const int E  = in_sizes[5];
    const int ER = in_sizes[10];
    const int EE = in_sizes[12];

    float* out = (float*)d_out;
    float* att_out = out + (size_t)N * LDO;

    const int TB = 256;
    int maxE = E > EE ? E : EE; if (ER > maxE) maxE = ER;

    // ---- workspace ----
    char* w = (char*)d_ws;
    int* deg3    = (int*)w;  w += (size_t)3 * N * 4;
    int* tot3    = (int*)w;  w += 4 * 4;                 // 3 counters (+pad), memset with deg3
    int* start3  = (int*)w;  w += (size_t)3 * N * 4;
    int* cur3    = (int*)w;  w += (size_t)3 * N * 4;
    int* col_adj = (int*)w;  w += (size_t)E * 4;
    int* eid_adj = (int*)w;  w += (size_t)E * 4;
    int* col_ent = (int*)w;  w += (size_t)EE * 4;
    int* col_rel = (int*)w;  w += (size_t)ER * 4;
    float* rel_attn_s = (float*)w;  w += (size_t)E * 4;
    float* proj       = (float*)w;  w += (size_t)R * 4;
    float* a_s0       = (float*)w;  w += (size_t)N * 4;
    float* a_n0       = (float*)w;  w += (size_t)N * 4;
    float* a_s1       = (float*)w;  w += (size_t)N * 4;
    float* a_n1       = (float*)w;  w += (size_t)N * 4;

    int* st_adj = start3;          int* dg_adj = deg3;
    int* st_ent = start3 + N;      int* dg_ent = deg3 + N;
    int* st_rel = start3 + 2 * N;  int* dg_rel = deg3 + 2 * N;

    // ---- rel projection (tiny; needed by scatter3) ----
    rel_proj_k<<<(R + TB - 1) / TB, TB, 0, stream>>>(rel_emb, a_rel, proj, R);

    // ---- CSR build: count -> ticket-alloc -> scatter(+rel_attn fused) ----
    hipMemsetAsync(deg3, 0, ((size_t)3 * N + 4) * sizeof(int), stream);  // deg3 + tot3
    {
        dim3 g((maxE + TB - 1) / TB, 3);
        count3_k<<<g, TB, 0, stream>>>(adj_row, ent_row, rel_row, E, EE, ER, deg3, N);
    }
    {
        dim3 g((N + TB - 1) / TB, 3);
        alloc3_k<<<g, TB, 0, stream>>>(deg3, tot3, start3, cur3, N);
    }
    {
        dim3 g((maxE + TB - 1) / TB, 3);
        scatter3_k<<<g, TB, 0, stream>>>(adj_row, adj_col, ent_row, ent_col, rel_row, rel_col,
                                         E, EE, ER, cur3, col_adj, eid_adj, col_ent, col_rel,
                                         sp_val, sp_col, proj, rel_attn_s, N);
    }

    // ---- initial features + depth-1 a_s/a_n ----
    meanagg_fused_k<<<(N + 3) / 4, 256, 0, stream>>>(st_ent, dg_ent, col_ent,
                                                     st_rel, dg_rel, col_rel,
                                                     ent_emb, rel_emb, a_self, a_neigh,
                                                     out, a_s0, a_n0, N);

    // ---- depth 1 ----
    attn_agg_fused_k<<<(N + 3) / 4, 256, 0, stream>>>(st_adj, dg_adj, col_adj, eid_adj,
                                                      rel_attn_s, a_s0, a_n0, a_self, a_neigh,
                                                      a_s1, a_n1, out, 0, ENT_F, nullptr, N);

    // ---- depth 2 ----
    attn_agg_fused_k<<<(N + 3) / 4, 256, 0, stream>>>(st_adj, dg_adj, col_adj, eid_adj,
                                                      rel_attn_s, a_s1, a_n1, nullptr, nullptr,
                                                      nullptr, nullptr, out, ENT_F, 2 * ENT_F,
                                                      att_out, N);
}

// Round 7
// 378.537 us; speedup vs baseline: 1.1323x; 1.0251x over previous
//
#include <hip/hip_runtime.h>

#define NODE_F 128
#define ENT_F  256
#define LDO    768   // out row stride: ENT_F * (DEPTH+1)
#define NEG_INF -3.4e38f

typedef float vf4 __attribute__((ext_vector_type(4)));

// ================= CSR build (blockIdx.y = graph: 0=adj,1=ent,2=rel) =================

__global__ void count3_k(const int* __restrict__ r0, const int* __restrict__ r1,
                         const int* __restrict__ r2, int E0, int E1, int E2,
                         int* __restrict__ deg3, int N) {
    int i = blockIdx.x * blockDim.x + threadIdx.x;
    int y = blockIdx.y;
    const int* rp = (y == 0) ? r0 : (y == 1) ? r1 : r2;
    int Eg = (y == 0) ? E0 : (y == 1) ? E1 : E2;
    if (i < Eg) atomicAdd(&deg3[(size_t)y * N + rp[i]], 1);
}

// ticket allocator: per-wave inclusive scan of degrees + one atomicAdd per wave.
__global__ void alloc3_k(const int* __restrict__ deg3, int* __restrict__ tot3,
                         int* __restrict__ start3, int* __restrict__ cur3, int N) {
    int y = blockIdx.y;
    int i = blockIdx.x * blockDim.x + threadIdx.x;
    int lane = threadIdx.x & 63;
    int d = (i < N) ? deg3[(size_t)y * N + i] : 0;
    int v = d;
    #pragma unroll
    for (int o = 1; o < 64; o <<= 1) {
        int t = __shfl_up(v, o);
        if (lane >= o) v += t;
    }
    int wsum = __shfl(v, 63);
    int base = 0;
    if (lane == 63) base = atomicAdd(&tot3[y], wsum);
    base = __shfl(base, 63);
    if (i < N) {
        int st = base + v - d;
        start3[(size_t)y * N + i] = st;
        cur3[(size_t)y * N + i] = st;
    }
}

// scatter; for adj also store row id and fused rel_attn (sp_row == arange(E)).
__global__ void scatter3_k(const int* __restrict__ r0, const int* __restrict__ c0,
                           const int* __restrict__ r1, const int* __restrict__ c1,
                           const int* __restrict__ r2, const int* __restrict__ c2,
                           int E0, int E1, int E2, int* __restrict__ cur3,
                           int* __restrict__ col_adj, int* __restrict__ eid_adj,
                           int* __restrict__ row_adj,
                           int* __restrict__ col_ent, int* __restrict__ col_rel,
                           const float* __restrict__ sp_val, const int* __restrict__ sp_col,
                           const float* __restrict__ proj, float* __restrict__ rel_attn_s,
                           int N) {
    int e = blockIdx.x * blockDim.x + threadIdx.x;
    int y = blockIdx.y;
    const int* rp = (y == 0) ? r0 : (y == 1) ? r1 : r2;
    const int* cp = (y == 0) ? c0 : (y == 1) ? c1 : c2;
    int* colp = (y == 0) ? col_adj : (y == 1) ? col_ent : col_rel;
    int Eg = (y == 0) ? E0 : (y == 1) ? E1 : E2;
    if (e >= Eg) return;
    int r = rp[e];
    int pos = atomicAdd(&cur3[(size_t)y * N + r], 1);
    colp[pos] = cp[e];
    if (y == 0) {
        eid_adj[pos] = e;
        row_adj[pos] = r;
        rel_attn_s[pos] = sp_val[e] * proj[sp_col[e]];
    }
}

__global__ void rel_proj_k(const float* __restrict__ rel_emb, const float* __restrict__ a_rel,
                           float* __restrict__ proj, int R) {
    int r = blockIdx.x * blockDim.x + threadIdx.x;
    if (r >= R) return;
    float s = 0.0f;
    #pragma unroll 4
    for (int f = 0; f < NODE_F; ++f) s += rel_emb[(size_t)r * NODE_F + f] * a_rel[f];
    proj[r] = s;
}

// per-edge attention logit (flat, all lanes active, latency fully hidden by TLP)
__global__ void edge_att_k(const int* __restrict__ row_s, const int* __restrict__ col_s,
                           const float* __restrict__ rel_attn_s,
                           const float* __restrict__ a_s, const float* __restrict__ a_n,
                           float* __restrict__ att_raw, int E) {
    int p = blockIdx.x * blockDim.x + threadIdx.x;
    if (p >= E) return;
    float v = rel_attn_s[p] + a_s[row_s[p]] + a_n[col_s[p]];
    att_raw[p] = v >= 0.0f ? v : 0.2f * v;   // leaky relu
}

// ================= fused feature kernels =================

// one wave per node: ent-mean + rel-mean, relu, write out, a_s/a_n dots in-register.
__global__ void meanagg_fused_k(const int* __restrict__ st_ent, const int* __restrict__ dg_ent,
                                const int* __restrict__ col_ent,
                                const int* __restrict__ st_rel, const int* __restrict__ dg_rel,
                                const int* __restrict__ col_rel,
                                const float* __restrict__ ent_emb, const float* __restrict__ rel_emb,
                                const float* __restrict__ a_self, const float* __restrict__ a_neigh,
                                float* __restrict__ out,
                                float* __restrict__ a_s_out, float* __restrict__ a_n_out, int N) {
    int n = blockIdx.x * (blockDim.x >> 6) + (threadIdx.x >> 6);
    int lane = threadIdx.x & 63;
    if (n >= N) return;

    float2 ea = {0.0f, 0.0f};
    {
        int s = st_ent[n], deg = dg_ent[n];
        int p = 0;
        for (; p + 4 <= deg; p += 4) {
            int c0 = col_ent[s + p], c1 = col_ent[s + p + 1];
            int c2 = col_ent[s + p + 2], c3 = col_ent[s + p + 3];
            float2 v0 = reinterpret_cast<const float2*>(&ent_emb[(size_t)c0 * NODE_F])[lane];
            float2 v1 = reinterpret_cast<const float2*>(&ent_emb[(size_t)c1 * NODE_F])[lane];
            float2 v2 = reinterpret_cast<const float2*>(&ent_emb[(size_t)c2 * NODE_F])[lane];
            float2 v3 = reinterpret_cast<const float2*>(&ent_emb[(size_t)c3 * NODE_F])[lane];
            ea.x += v0.x + v1.x + v2.x + v3.x;
            ea.y += v0.y + v1.y + v2.y + v3.y;
        }
        for (; p < deg; ++p) {
            float2 v = reinterpret_cast<const float2*>(&ent_emb[(size_t)col_ent[s + p] * NODE_F])[lane];
            ea.x += v.x; ea.y += v.y;
        }
        if (deg > 0) { float w = 1.0f / (float)deg; ea.x *= w; ea.y *= w; }
    }

    float2 ra = {0.0f, 0.0f};
    {
        int s = st_rel[n], deg = dg_rel[n];
        int p = 0;
        for (; p + 4 <= deg; p += 4) {
            int c0 = col_rel[s + p], c1 = col_rel[s + p + 1];
            int c2 = col_rel[s + p + 2], c3 = col_rel[s + p + 3];
            float2 v0 = reinterpret_cast<const float2*>(&rel_emb[(size_t)c0 * NODE_F])[lane];
            float2 v1 = reinterpret_cast<const float2*>(&rel_emb[(size_t)c1 * NODE_F])[lane];
            float2 v2 = reinterpret_cast<const float2*>(&rel_emb[(size_t)c2 * NODE_F])[lane];
            float2 v3 = reinterpret_cast<const float2*>(&rel_emb[(size_t)c3 * NODE_F])[lane];
            ra.x += v0.x + v1.x + v2.x + v3.x;
            ra.y += v0.y + v1.y + v2.y + v3.y;
        }
        for (; p < deg; ++p) {
            float2 v = reinterpret_cast<const float2*>(&rel_emb[(size_t)col_rel[s + p] * NODE_F])[lane];
            ra.x += v.x; ra.y += v.y;
        }
        if (deg > 0) { float w = 1.0f / (float)deg; ra.x *= w; ra.y *= w; }
    }

    ea.x = ea.x > 0.0f ? ea.x : 0.0f;  ea.y = ea.y > 0.0f ? ea.y : 0.0f;
    ra.x = ra.x > 0.0f ? ra.x : 0.0f;  ra.y = ra.y > 0.0f ? ra.y : 0.0f;

    reinterpret_cast<float2*>(&out[(size_t)n * LDO])[lane] = ea;
    reinterpret_cast<float2*>(&out[(size_t)n * LDO + NODE_F])[lane] = ra;

    float2 se = reinterpret_cast<const float2*>(a_self)[lane];
    float2 sr = reinterpret_cast<const float2*>(a_self)[64 + lane];
    float2 ne = reinterpret_cast<const float2*>(a_neigh)[lane];
    float2 nr = reinterpret_cast<const float2*>(a_neigh)[64 + lane];
    float ds = ea.x * se.x + ea.y * se.y + ra.x * sr.x + ra.y * sr.y;
    float dn = ea.x * ne.x + ea.y * ne.y + ra.x * nr.x + ra.y * nr.y;
    #pragma unroll
    for (int o = 32; o > 0; o >>= 1) {
        ds += __shfl_xor(ds, o);
        dn += __shfl_xor(dn, o);
    }
    if (lane == 0) { a_s_out[n] = ds; a_n_out[n] = dn; }
}

// one wave per node: softmax from precomputed att_raw + weighted gather (4-wide MLP)
// + relu + optional next-depth a_s/a_n + optional att scatter. NT: nontemporal stores.
template <int NT>
__global__ void attn_agg_slim_k(const int* __restrict__ st, const int* __restrict__ dg,
                                const int* __restrict__ col_s, const int* __restrict__ eid_s,
                                const float* __restrict__ att_raw,
                                const float* __restrict__ a_self, const float* __restrict__ a_neigh,
                                float* __restrict__ a_s_out, float* __restrict__ a_n_out,
                                float* __restrict__ out, int src, int dst,
                                float* __restrict__ att_out, int N) {
    int n = blockIdx.x * (blockDim.x >> 6) + (threadIdx.x >> 6);
    int lane = threadIdx.x & 63;
    if (n >= N) return;
    int s = st[n];
    int deg = dg[n];
    float4 acc = {0.0f, 0.0f, 0.0f, 0.0f};

    if (deg > 0) {
        if (deg <= 64) {
            float myv = NEG_INF;
            int mycol = 0;
            if (lane < deg) {
                mycol = col_s[s + lane];
                myv = att_raw[s + lane];
            }
            float m = myv;
            #pragma unroll
            for (int o = 32; o > 0; o >>= 1) {
                float x = __shfl_xor(m, o);
                m = x > m ? x : m;
            }
            float ex = (lane < deg) ? __expf(myv - m) : 0.0f;
            float ssum = ex;
            #pragma unroll
            for (int o = 32; o > 0; o >>= 1) ssum += __shfl_xor(ssum, o);
            float myatt = ex / ssum;
            if (att_out && lane < deg) {
                if (NT) __builtin_nontemporal_store(myatt, &att_out[eid_s[s + lane]]);
                else    att_out[eid_s[s + lane]] = myatt;
            }

            int p = 0;
            for (; p + 4 <= deg; p += 4) {
                float a0 = __shfl(myatt, p),     a1 = __shfl(myatt, p + 1);
                float a2 = __shfl(myatt, p + 2), a3 = __shfl(myatt, p + 3);
                int c0 = __shfl(mycol, p),     c1 = __shfl(mycol, p + 1);
                int c2 = __shfl(mycol, p + 2), c3 = __shfl(mycol, p + 3);
                float4 v0 = reinterpret_cast<const float4*>(&out[(size_t)c0 * LDO + src])[lane];
                float4 v1 = reinterpret_cast<const float4*>(&out[(size_t)c1 * LDO + src])[lane];
                float4 v2 = reinterpret_cast<const float4*>(&out[(size_t)c2 * LDO + src])[lane];
                float4 v3 = reinterpret_cast<const float4*>(&out[(size_t)c3 * LDO + src])[lane];
                acc.x += a0 * v0.x + a1 * v1.x + a2 * v2.x + a3 * v3.x;
                acc.y += a0 * v0.y + a1 * v1.y + a2 * v2.y + a3 * v3.y;
                acc.z += a0 * v0.z + a1 * v1.z + a2 * v2.z + a3 * v3.z;
                acc.w += a0 * v0.w + a1 * v1.w + a2 * v2.w + a3 * v3.w;
            }
            for (; p < deg; ++p) {
                float a = __shfl(myatt, p);
                int c = __shfl(mycol, p);
                float4 v = reinterpret_cast<const float4*>(&out[(size_t)c * LDO + src])[lane];
                acc.x += a * v.x; acc.y += a * v.y; acc.z += a * v.z; acc.w += a * v.w;
            }
        } else {  // rare fallback: deg > 64
            float m = NEG_INF;
            for (int p = s + lane; p < s + deg; p += 64) {
                float v = att_raw[p];
                m = v > m ? v : m;
            }
            #pragma unroll
            for (int o = 32; o > 0; o >>= 1) {
                float x = __shfl_xor(m, o);
                m = x > m ? x : m;
            }
            float ssum = 0.0f;
            for (int p = s + lane; p < s + deg; p += 64) ssum += __expf(att_raw[p] - m);
            #pragma unroll
            for (int o = 32; o > 0; o >>= 1) ssum += __shfl_xor(ssum, o);
            float inv = 1.0f / ssum;
            for (int p = s; p < s + deg; ++p) {
                int c = col_s[p];
                float a = __expf(att_raw[p] - m) * inv;
                if (att_out && lane == 0) att_out[eid_s[p]] = a;
                float4 fv = reinterpret_cast<const float4*>(&out[(size_t)c * LDO + src])[lane];
                acc.x += a * fv.x; acc.y += a * fv.y; acc.z += a * fv.z; acc.w += a * fv.w;
            }
        }
    }

    acc.x = acc.x > 0.0f ? acc.x : 0.0f;
    acc.y = acc.y > 0.0f ? acc.y : 0.0f;
    acc.z = acc.z > 0.0f ? acc.z : 0.0f;
    acc.w = acc.w > 0.0f ? acc.w : 0.0f;
    float* dstp = &out[(size_t)n * LDO + dst] + (size_t)lane * 4;
    if (NT) {
        vf4 v; v.x = acc.x; v.y = acc.y; v.z = acc.z; v.w = acc.w;
        __builtin_nontemporal_store(v, reinterpret_cast<vf4*>(dstp));
    } else {
        *reinterpret_cast<float4*>(dstp) = acc;
    }

    if (a_s_out) {
        float4 s4 = reinterpret_cast<const float4*>(a_self)[lane];
        float4 n4 = reinterpret_cast<const float4*>(a_neigh)[lane];
        float ds = acc.x * s4.x + acc.y * s4.y + acc.z * s4.z + acc.w * s4.w;
        float dn = acc.x * n4.x + acc.y * n4.y + acc.z * n4.z + acc.w * n4.w;
        #pragma unroll
        for (int o = 32; o > 0; o >>= 1) {
            ds += __shfl_xor(ds, o);
            dn += __shfl_xor(dn, o);
        }
        if (lane == 0) { a_s_out[n] = ds; a_n_out[n] = dn; }
    }
}

// ================= launch =================

extern "C" void kernel_launch(void* const* d_in, const int* in_sizes, int n_in,
                              void* d_out, int out_size, void* d_ws, size_t ws_size,
                              hipStream_t stream) {
    const float* ent_emb = (const float*)d_in[0];
    const float* rel_emb = (const float*)d_in[1];
    const float* a_self  = (const float*)d_in[2];
    const float* a_neigh = (const float*)d_in[3];
    const float* a_rel   = (const float*)d_in[4];
    const float* sp_val  = (const float*)d_in[5];
    const int*   adj_row = (const int*)d_in[6];
    const int*   adj_col = (const int*)d_in[7];
    const int*   sp_col  = (const int*)d_in[9];
    const int*   rel_row = (const int*)d_in[10];
    const int*   rel_col = (const int*)d_in[11];
    const int*   ent_row = (const int*)d_in[12];
    const int*   ent_col = (const int*)d_in[13];

    const int N  = in_sizes[0] / NODE_F;
    const int R  = in_sizes[1] / NODE_F;
    const int E  = in_sizes[5];
    const int ER = in_sizes[10];
    const int EE = in_sizes[12];

    float* out = (float*)d_out;
    float* att_out = out + (size_t)N * LDO;

    const int TB = 256;
    int maxE = E > EE ? E : EE; if (ER > maxE) maxE = ER;

    // ---- workspace ----
    char* w = (char*)d_ws;
    int* deg3    = (int*)w;  w += (size_t)3 * N * 4;
    int* tot3    = (int*)w;  w += 4 * 4;                 // 3 counters (+pad), memset with deg3
    int* start3  = (int*)w;  w += (size_t)3 * N * 4;
    int* cur3    = (int*)w;  w += (size_t)3 * N * 4;
    int* col_adj = (int*)w;  w += (size_t)E * 4;
    int* eid_adj = (int*)w;  w += (size_t)E * 4;
    int* row_adj = (int*)w;  w += (size_t)E * 4;
    int* col_ent = (int*)w;  w += (size_t)EE * 4;
    int* col_rel = (int*)w;  w += (size_t)ER * 4;
    float* rel_attn_s = (float*)w;  w += (size_t)E * 4;
    float* att_raw    = (float*)w;  w += (size_t)E * 4;
    float* proj       = (float*)w;  w += (size_t)R * 4;
    float* a_s0       = (float*)w;  w += (size_t)N * 4;
    float* a_n0       = (float*)w;  w += (size_t)N * 4;
    float* a_s1       = (float*)w;  w += (size_t)N * 4;
    float* a_n1       = (float*)w;  w += (size_t)N * 4;

    int* st_adj = start3;          int* dg_adj = deg3;
    int* st_ent = start3 + N;      int* dg_ent = deg3 + N;
    int* st_rel = start3 + 2 * N;  int* dg_rel = deg3 + 2 * N;

    const int gE = (E + TB - 1) / TB;

    // ---- rel projection (tiny; needed by scatter3) ----
    rel_proj_k<<<(R + TB - 1) / TB, TB, 0, stream>>>(rel_emb, a_rel, proj, R);

    // ---- CSR build: count -> ticket-alloc -> scatter(+rel_attn fused) ----
    hipMemsetAsync(deg3, 0, ((size_t)3 * N + 4) * sizeof(int), stream);  // deg3 + tot3
    {
        dim3 g((maxE + TB - 1) / TB, 3);
        count3_k<<<g, TB, 0, stream>>>(adj_row, ent_row, rel_row, E, EE, ER, deg3, N);
    }
    {
        dim3 g((N + TB - 1) / TB, 3);
        alloc3_k<<<g, TB, 0, stream>>>(deg3, tot3, start3, cur3, N);
    }
    {
        dim3 g((maxE + TB - 1) / TB, 3);
        scatter3_k<<<g, TB, 0, stream>>>(adj_row, adj_col, ent_row, ent_col, rel_row, rel_col,
                                         E, EE, ER, cur3, col_adj, eid_adj, row_adj,
                                         col_ent, col_rel, sp_val, sp_col, proj, rel_attn_s, N);
    }

    // ---- initial features + depth-1 a_s/a_n ----
    meanagg_fused_k<<<(N + 3) / 4, 256, 0, stream>>>(st_ent, dg_ent, col_ent,
                                                     st_rel, dg_rel, col_rel,
                                                     ent_emb, rel_emb, a_self, a_neigh,
                                                     out, a_s0, a_n0, N);

    // ---- depth 1 ----
    edge_att_k<<<gE, TB, 0, stream>>>(row_adj, col_adj, rel_attn_s, a_s0, a_n0, att_raw, E);
    attn_agg_slim_k<0><<<(N + 3) / 4, 256, 0, stream>>>(st_adj, dg_adj, col_adj, eid_adj,
                                                        att_raw, a_self, a_neigh, a_s1, a_n1,
                                                        out, 0, ENT_F, nullptr, N);

    // ---- depth 2 (nontemporal final stores) ----
    edge_att_k<<<gE, TB, 0, stream>>>(row_adj, col_adj, rel_attn_s, a_s1, a_n1, att_raw, E);
    attn_agg_slim_k<1><<<(N + 3) / 4, 256, 0, stream>>>(st_adj, dg_adj, col_adj, eid_adj,
                                                        att_raw, nullptr, nullptr, nullptr, nullptr,
                                                        out, ENT_F, 2 * ENT_F, att_out, N);
}

// Round 8
// 345.537 us; speedup vs baseline: 1.2405x; 1.0955x over previous
//
#include <hip/hip_runtime.h>

#define NODE_F 128
#define ENT_F  256
#define LDO    768   // out row stride: ENT_F * (DEPTH+1)
#define NEG_INF -3.4e38f

typedef float vf4 __attribute__((ext_vector_type(4)));

// ================= CSR build (blockIdx.y = graph: 0=adj,1=ent,2=rel) =================

__global__ void count3_k(const int* __restrict__ r0, const int* __restrict__ r1,
                         const int* __restrict__ r2, int E0, int E1, int E2,
                         int* __restrict__ deg3, int N) {
    int i = blockIdx.x * blockDim.x + threadIdx.x;
    int y = blockIdx.y;
    const int* rp = (y == 0) ? r0 : (y == 1) ? r1 : r2;
    int Eg = (y == 0) ? E0 : (y == 1) ? E1 : E2;
    if (i < Eg) atomicAdd(&deg3[(size_t)y * N + rp[i]], 1);
}

// per-256-chunk sums of deg
__global__ void blocksum3_k(const int* __restrict__ deg3, int* __restrict__ bs3, int N) {
    __shared__ int s[256];
    int y = blockIdx.y;
    int i = blockIdx.x * 256 + threadIdx.x;
    s[threadIdx.x] = (i < N) ? deg3[(size_t)y * N + i] : 0;
    __syncthreads();
    for (int o = 128; o > 0; o >>= 1) {
        if (threadIdx.x < o) s[threadIdx.x] += s[threadIdx.x + o];
        __syncthreads();
    }
    if (threadIdx.x == 0) bs3[y * 512 + blockIdx.x] = s[0];
}

// exclusive scan of each graph's block sums (nb <= 512)
__global__ void scanbsum3_k(int* __restrict__ bs3, int nb) {
    __shared__ int s[512];
    int y = blockIdx.x;
    int tid = threadIdx.x;
    int v = (tid < nb) ? bs3[y * 512 + tid] : 0;
    s[tid] = v;
    __syncthreads();
    for (int o = 1; o < 512; o <<= 1) {
        int t = (tid >= o) ? s[tid - o] : 0;
        __syncthreads();
        s[tid] += t;
        __syncthreads();
    }
    if (tid < nb) bs3[y * 512 + tid] = s[tid] - v;      // exclusive
}

// per-chunk exclusive scan + chunk offset -> row_start (rs3) and scatter cursor (cur3)
__global__ void scandeg3_k(const int* __restrict__ deg3, const int* __restrict__ bs3,
                           int* __restrict__ rs3, int* __restrict__ cur3, int N) {
    __shared__ int s[256];
    int y = blockIdx.y;
    int i = blockIdx.x * 256 + threadIdx.x;
    int v = (i < N) ? deg3[(size_t)y * N + i] : 0;
    s[threadIdx.x] = v;
    __syncthreads();
    for (int o = 1; o < 256; o <<= 1) {
        int t = (threadIdx.x >= o) ? s[threadIdx.x - o] : 0;
        __syncthreads();
        s[threadIdx.x] += t;
        __syncthreads();
    }
    if (i < N) {
        int rs = bs3[y * 512 + blockIdx.x] + s[threadIdx.x] - v;
        rs3[(size_t)y * N + i] = rs;
        cur3[(size_t)y * N + i] = rs;
    }
}

// scatter; for adj also store row id, eid, and fused rel_attn (sp_row == arange(E)).
__global__ void scatter3_k(const int* __restrict__ r0, const int* __restrict__ c0,
                           const int* __restrict__ r1, const int* __restrict__ c1,
                           const int* __restrict__ r2, const int* __restrict__ c2,
                           int E0, int E1, int E2, int* __restrict__ cur3,
                           int* __restrict__ col_adj, int* __restrict__ eid_adj,
                           int* __restrict__ row_adj,
                           int* __restrict__ col_ent, int* __restrict__ col_rel,
                           const float* __restrict__ sp_val, const int* __restrict__ sp_col,
                           const float* __restrict__ proj, float* __restrict__ rel_attn_s,
                           int N) {
    int e = blockIdx.x * blockDim.x + threadIdx.x;
    int y = blockIdx.y;
    const int* rp = (y == 0) ? r0 : (y == 1) ? r1 : r2;
    const int* cp = (y == 0) ? c0 : (y == 1) ? c1 : c2;
    int* colp = (y == 0) ? col_adj : (y == 1) ? col_ent : col_rel;
    int Eg = (y == 0) ? E0 : (y == 1) ? E1 : E2;
    if (e >= Eg) return;
    int r = rp[e];
    int pos = atomicAdd(&cur3[(size_t)y * N + r], 1);
    colp[pos] = cp[e];
    if (y == 0) {
        eid_adj[pos] = e;
        row_adj[pos] = r;
        rel_attn_s[pos] = sp_val[e] * proj[sp_col[e]];
    }
}

__global__ void rel_proj_k(const float* __restrict__ rel_emb, const float* __restrict__ a_rel,
                           float* __restrict__ proj, int R) {
    int r = blockIdx.x * blockDim.x + threadIdx.x;
    if (r >= R) return;
    float s = 0.0f;
    #pragma unroll 4
    for (int f = 0; f < NODE_F; ++f) s += rel_emb[(size_t)r * NODE_F + f] * a_rel[f];
    proj[r] = s;
}

// per-edge attention logit (flat, all lanes active, latency fully hidden by TLP)
__global__ void edge_att_k(const int* __restrict__ row_s, const int* __restrict__ col_s,
                           const float* __restrict__ rel_attn_s,
                           const float* __restrict__ a_s, const float* __restrict__ a_n,
                           float* __restrict__ att_raw, int E) {
    int p = blockIdx.x * blockDim.x + threadIdx.x;
    if (p >= E) return;
    float v = rel_attn_s[p] + a_s[row_s[p]] + a_n[col_s[p]];
    att_raw[p] = v >= 0.0f ? v : 0.2f * v;   // leaky relu
}

// ================= fused feature kernels =================

// one wave per node: ent-mean + rel-mean, relu, write out, a_s/a_n dots in-register.
__global__ void meanagg_fused_k(const int* __restrict__ st_ent, const int* __restrict__ dg_ent,
                                const int* __restrict__ col_ent,
                                const int* __restrict__ st_rel, const int* __restrict__ dg_rel,
                                const int* __restrict__ col_rel,
                                const float* __restrict__ ent_emb, const float* __restrict__ rel_emb,
                                const float* __restrict__ a_self, const float* __restrict__ a_neigh,
                                float* __restrict__ out,
                                float* __restrict__ a_s_out, float* __restrict__ a_n_out, int N) {
    int n = blockIdx.x * (blockDim.x >> 6) + (threadIdx.x >> 6);
    int lane = threadIdx.x & 63;
    if (n >= N) return;

    float2 ea = {0.0f, 0.0f};
    {
        int s = st_ent[n], deg = dg_ent[n];
        for (int p = s; p < s + deg; ++p) {
            float2 v = reinterpret_cast<const float2*>(&ent_emb[(size_t)col_ent[p] * NODE_F])[lane];
            ea.x += v.x; ea.y += v.y;
        }
        if (deg > 0) { float w = 1.0f / (float)deg; ea.x *= w; ea.y *= w; }
    }

    float2 ra = {0.0f, 0.0f};
    {
        int s = st_rel[n], deg = dg_rel[n];
        for (int p = s; p < s + deg; ++p) {
            float2 v = reinterpret_cast<const float2*>(&rel_emb[(size_t)col_rel[p] * NODE_F])[lane];
            ra.x += v.x; ra.y += v.y;
        }
        if (deg > 0) { float w = 1.0f / (float)deg; ra.x *= w; ra.y *= w; }
    }

    ea.x = ea.x > 0.0f ? ea.x : 0.0f;  ea.y = ea.y > 0.0f ? ea.y : 0.0f;
    ra.x = ra.x > 0.0f ? ra.x : 0.0f;  ra.y = ra.y > 0.0f ? ra.y : 0.0f;

    reinterpret_cast<float2*>(&out[(size_t)n * LDO])[lane] = ea;
    reinterpret_cast<float2*>(&out[(size_t)n * LDO + NODE_F])[lane] = ra;

    float2 se = reinterpret_cast<const float2*>(a_self)[lane];
    float2 sr = reinterpret_cast<const float2*>(a_self)[64 + lane];
    float2 ne = reinterpret_cast<const float2*>(a_neigh)[lane];
    float2 nr = reinterpret_cast<const float2*>(a_neigh)[64 + lane];
    float ds = ea.x * se.x + ea.y * se.y + ra.x * sr.x + ra.y * sr.y;
    float dn = ea.x * ne.x + ea.y * ne.y + ra.x * nr.x + ra.y * nr.y;
    #pragma unroll
    for (int o = 32; o > 0; o >>= 1) {
        ds += __shfl_xor(ds, o);
        dn += __shfl_xor(dn, o);
    }
    if (lane == 0) { a_s_out[n] = ds; a_n_out[n] = dn; }
}

// one wave per node: softmax from precomputed att_raw + weighted gather + relu
// + optional next-depth a_s/a_n + optional att scatter. NT: nontemporal stores.
template <int NT>
__global__ void attn_agg_slim_k(const int* __restrict__ st, const int* __restrict__ dg,
                                const int* __restrict__ col_s, const int* __restrict__ eid_s,
                                const float* __restrict__ att_raw,
                                const float* __restrict__ a_self, const float* __restrict__ a_neigh,
                                float* __restrict__ a_s_out, float* __restrict__ a_n_out,
                                float* __restrict__ out, int src, int dst,
                                float* __restrict__ att_out, int N) {
    int n = blockIdx.x * (blockDim.x >> 6) + (threadIdx.x >> 6);
    int lane = threadIdx.x & 63;
    if (n >= N) return;
    int s = st[n];
    int deg = dg[n];
    float4 acc = {0.0f, 0.0f, 0.0f, 0.0f};

    if (deg > 0) {
        if (deg <= 64) {
            float myv = NEG_INF;
            int mycol = 0;
            if (lane < deg) {
                mycol = col_s[s + lane];
                myv = att_raw[s + lane];
            }
            float m = myv;
            #pragma unroll
            for (int o = 32; o > 0; o >>= 1) {
                float x = __shfl_xor(m, o);
                m = x > m ? x : m;
            }
            float ex = (lane < deg) ? __expf(myv - m) : 0.0f;
            float ssum = ex;
            #pragma unroll
            for (int o = 32; o > 0; o >>= 1) ssum += __shfl_xor(ssum, o);
            float myatt = ex / ssum;
            if (att_out && lane < deg) {
                if (NT) __builtin_nontemporal_store(myatt, &att_out[eid_s[s + lane]]);
                else    att_out[eid_s[s + lane]] = myatt;
            }
            for (int p = 0; p < deg; ++p) {
                float a = __shfl(myatt, p);
                int c = __shfl(mycol, p);
                float4 v = reinterpret_cast<const float4*>(&out[(size_t)c * LDO + src])[lane];
                acc.x += a * v.x; acc.y += a * v.y; acc.z += a * v.z; acc.w += a * v.w;
            }
        } else {  // rare fallback: deg > 64
            float m = NEG_INF;
            for (int p = s + lane; p < s + deg; p += 64) {
                float v = att_raw[p];
                m = v > m ? v : m;
            }
            #pragma unroll
            for (int o = 32; o > 0; o >>= 1) {
                float x = __shfl_xor(m, o);
                m = x > m ? x : m;
            }
            float ssum = 0.0f;
            for (int p = s + lane; p < s + deg; p += 64) ssum += __expf(att_raw[p] - m);
            #pragma unroll
            for (int o = 32; o > 0; o >>= 1) ssum += __shfl_xor(ssum, o);
            float inv = 1.0f / ssum;
            for (int p = s; p < s + deg; ++p) {
                int c = col_s[p];
                float a = __expf(att_raw[p] - m) * inv;
                if (att_out && lane == 0) att_out[eid_s[p]] = a;
                float4 fv = reinterpret_cast<const float4*>(&out[(size_t)c * LDO + src])[lane];
                acc.x += a * fv.x; acc.y += a * fv.y; acc.z += a * fv.z; acc.w += a * fv.w;
            }
        }
    }

    acc.x = acc.x > 0.0f ? acc.x : 0.0f;
    acc.y = acc.y > 0.0f ? acc.y : 0.0f;
    acc.z = acc.z > 0.0f ? acc.z : 0.0f;
    acc.w = acc.w > 0.0f ? acc.w : 0.0f;
    float* dstp = &out[(size_t)n * LDO + dst] + (size_t)lane * 4;
    if (NT) {
        vf4 v; v.x = acc.x; v.y = acc.y; v.z = acc.z; v.w = acc.w;
        __builtin_nontemporal_store(v, reinterpret_cast<vf4*>(dstp));
    } else {
        *reinterpret_cast<float4*>(dstp) = acc;
    }

    if (a_s_out) {
        float4 s4 = reinterpret_cast<const float4*>(a_self)[lane];
        float4 n4 = reinterpret_cast<const float4*>(a_neigh)[lane];
        float ds = acc.x * s4.x + acc.y * s4.y + acc.z * s4.z + acc.w * s4.w;
        float dn = acc.x * n4.x + acc.y * n4.y + acc.z * n4.z + acc.w * n4.w;
        #pragma unroll
        for (int o = 32; o > 0; o >>= 1) {
            ds += __shfl_xor(ds, o);
            dn += __shfl_xor(dn, o);
        }
        if (lane == 0) { a_s_out[n] = ds; a_n_out[n] = dn; }
    }
}

// ================= launch =================

extern "C" void kernel_launch(void* const* d_in, const int* in_sizes, int n_in,
                              void* d_out, int out_size, void* d_ws, size_t ws_size,
                              hipStream_t stream) {
    const float* ent_emb = (const float*)d_in[0];
    const float* rel_emb = (const float*)d_in[1];
    const float* a_self  = (const float*)d_in[2];
    const float* a_neigh = (const float*)d_in[3];
    const float* a_rel   = (const float*)d_in[4];
    const float* sp_val  = (const float*)d_in[5];
    const int*   adj_row = (const int*)d_in[6];
    const int*   adj_col = (const int*)d_in[7];
    const int*   sp_col  = (const int*)d_in[9];
    const int*   rel_row = (const int*)d_in[10];
    const int*   rel_col = (const int*)d_in[11];
    const int*   ent_row = (const int*)d_in[12];
    const int*   ent_col = (const int*)d_in[13];

    const int N  = in_sizes[0] / NODE_F;
    const int R  = in_sizes[1] / NODE_F;
    const int E  = in_sizes[5];
    const int ER = in_sizes[10];
    const int EE = in_sizes[12];

    float* out = (float*)d_out;
    float* att_out = out + (size_t)N * LDO;

    const int TB = 256;
    const int nb = (N + 255) / 256;            // <= 512
    int maxE = E > EE ? E : EE; if (ER > maxE) maxE = ER;

    // ---- workspace ----
    char* w = (char*)d_ws;
    int* deg3    = (int*)w;  w += (size_t)3 * N * 4;
    int* rs3     = (int*)w;  w += (size_t)3 * N * 4;
    int* cur3    = (int*)w;  w += (size_t)3 * N * 4;
    int* bs3     = (int*)w;  w += (size_t)3 * 512 * 4;
    int* col_adj = (int*)w;  w += (size_t)E * 4;
    int* eid_adj = (int*)w;  w += (size_t)E * 4;
    int* row_adj = (int*)w;  w += (size_t)E * 4;
    int* col_ent = (int*)w;  w += (size_t)EE * 4;
    int* col_rel = (int*)w;  w += (size_t)ER * 4;
    float* rel_attn_s = (float*)w;  w += (size_t)E * 4;
    float* att_raw    = (float*)w;  w += (size_t)E * 4;
    float* proj       = (float*)w;  w += (size_t)R * 4;
    float* a_s0       = (float*)w;  w += (size_t)N * 4;
    float* a_n0       = (float*)w;  w += (size_t)N * 4;
    float* a_s1       = (float*)w;  w += (size_t)N * 4;
    float* a_n1       = (float*)w;  w += (size_t)N * 4;

    int* st_adj = rs3;          int* dg_adj = deg3;
    int* st_ent = rs3 + N;      int* dg_ent = deg3 + N;
    int* st_rel = rs3 + 2 * N;  int* dg_rel = deg3 + 2 * N;

    const int gE = (E + TB - 1) / TB;

    // ---- rel projection (tiny; needed by scatter3) ----
    rel_proj_k<<<(R + TB - 1) / TB, TB, 0, stream>>>(rel_emb, a_rel, proj, R);

    // ---- CSR build: count -> scan (monotone) -> scatter(+rel_attn fused) ----
    hipMemsetAsync(deg3, 0, (size_t)3 * N * sizeof(int), stream);
    {
        dim3 g((maxE + TB - 1) / TB, 3);
        count3_k<<<g, TB, 0, stream>>>(adj_row, ent_row, rel_row, E, EE, ER, deg3, N);
    }
    {
        dim3 g(nb, 3);
        blocksum3_k<<<g, 256, 0, stream>>>(deg3, bs3, N);
        scanbsum3_k<<<3, 512, 0, stream>>>(bs3, nb);
        scandeg3_k<<<g, 256, 0, stream>>>(deg3, bs3, rs3, cur3, N);
    }
    {
        dim3 g((maxE + TB - 1) / TB, 3);
        scatter3_k<<<g, TB, 0, stream>>>(adj_row, adj_col, ent_row, ent_col, rel_row, rel_col,
                                         E, EE, ER, cur3, col_adj, eid_adj, row_adj,
                                         col_ent, col_rel, sp_val, sp_col, proj, rel_attn_s, N);
    }

    // ---- initial features + depth-1 a_s/a_n ----
    meanagg_fused_k<<<(N + 3) / 4, 256, 0, stream>>>(st_ent, dg_ent, col_ent,
                                                     st_rel, dg_rel, col_rel,
                                                     ent_emb, rel_emb, a_self, a_neigh,
                                                     out, a_s0, a_n0, N);

    // ---- depth 1 ----
    edge_att_k<<<gE, TB, 0, stream>>>(row_adj, col_adj, rel_attn_s, a_s0, a_n0, att_raw, E);
    attn_agg_slim_k<0><<<(N + 3) / 4, 256, 0, stream>>>(st_adj, dg_adj, col_adj, eid_adj,
                                                        att_raw, a_self, a_neigh, a_s1, a_n1,
                                                        out, 0, ENT_F, nullptr, N);

    // ---- depth 2 (nontemporal final stores) ----
    edge_att_k<<<gE, TB, 0, stream>>>(row_adj, col_adj, rel_attn_s, a_s1, a_n1, att_raw, E);
    attn_agg_slim_k<1><<<(N + 3) / 4, 256, 0, stream>>>(st_adj, dg_adj, col_adj, eid_adj,
                                                        att_raw, nullptr, nullptr, nullptr, nullptr,
                                                        out, ENT_F, 2 * ENT_F, att_out, N);
}

// Round 9
// 328.675 us; speedup vs baseline: 1.3041x; 1.0513x over previous
//
#include <hip/hip_runtime.h>

#define NODE_F 128
#define ENT_F  256
#define LDO    768   // out row stride: ENT_F * (DEPTH+1)
#define NEG_INF -3.4e38f

typedef float vf4 __attribute__((ext_vector_type(4)));

// ================= CSR build (blockIdx.y = graph: 0=adj,1=ent,2=rel) =================

__global__ void count3_k(const int* __restrict__ r0, const int* __restrict__ r1,
                         const int* __restrict__ r2, int E0, int E1, int E2,
                         int* __restrict__ deg3, int N) {
    int i = blockIdx.x * blockDim.x + threadIdx.x;
    int y = blockIdx.y;
    const int* rp = (y == 0) ? r0 : (y == 1) ? r1 : r2;
    int Eg = (y == 0) ? E0 : (y == 1) ? E1 : E2;
    if (i < Eg) atomicAdd(&deg3[(size_t)y * N + rp[i]], 1);
}

// per-256-chunk sums of deg
__global__ void blocksum3_k(const int* __restrict__ deg3, int* __restrict__ bs3, int N) {
    __shared__ int s[256];
    int y = blockIdx.y;
    int i = blockIdx.x * 256 + threadIdx.x;
    s[threadIdx.x] = (i < N) ? deg3[(size_t)y * N + i] : 0;
    __syncthreads();
    for (int o = 128; o > 0; o >>= 1) {
        if (threadIdx.x < o) s[threadIdx.x] += s[threadIdx.x + o];
        __syncthreads();
    }
    if (threadIdx.x == 0) bs3[y * 512 + blockIdx.x] = s[0];
}

// exclusive scan of each graph's block sums (nb <= 512)
__global__ void scanbsum3_k(int* __restrict__ bs3, int nb) {
    __shared__ int s[512];
    int y = blockIdx.x;
    int tid = threadIdx.x;
    int v = (tid < nb) ? bs3[y * 512 + tid] : 0;
    s[tid] = v;
    __syncthreads();
    for (int o = 1; o < 512; o <<= 1) {
        int t = (tid >= o) ? s[tid - o] : 0;
        __syncthreads();
        s[tid] += t;
        __syncthreads();
    }
    if (tid < nb) bs3[y * 512 + tid] = s[tid] - v;      // exclusive
}

// per-chunk exclusive scan + chunk offset -> row_start (rs3) and scatter cursor (cur3)
__global__ void scandeg3_k(const int* __restrict__ deg3, const int* __restrict__ bs3,
                           int* __restrict__ rs3, int* __restrict__ cur3, int N) {
    __shared__ int s[256];
    int y = blockIdx.y;
    int i = blockIdx.x * 256 + threadIdx.x;
    int v = (i < N) ? deg3[(size_t)y * N + i] : 0;
    s[threadIdx.x] = v;
    __syncthreads();
    for (int o = 1; o < 256; o <<= 1) {
        int t = (threadIdx.x >= o) ? s[threadIdx.x - o] : 0;
        __syncthreads();
        s[threadIdx.x] += t;
        __syncthreads();
    }
    if (i < N) {
        int rs = bs3[y * 512 + blockIdx.x] + s[threadIdx.x] - v;
        rs3[(size_t)y * N + i] = rs;
        cur3[(size_t)y * N + i] = rs;
    }
}

// scatter; for adj also store row id, eid, and fused rel_attn (sp_row == arange(E)).
__global__ void scatter3_k(const int* __restrict__ r0, const int* __restrict__ c0,
                           const int* __restrict__ r1, const int* __restrict__ c1,
                           const int* __restrict__ r2, const int* __restrict__ c2,
                           int E0, int E1, int E2, int* __restrict__ cur3,
                           int* __restrict__ col_adj, int* __restrict__ eid_adj,
                           int* __restrict__ row_adj,
                           int* __restrict__ col_ent, int* __restrict__ col_rel,
                           const float* __restrict__ sp_val, const int* __restrict__ sp_col,
                           const float* __restrict__ proj, float* __restrict__ rel_attn_s,
                           int N) {
    int e = blockIdx.x * blockDim.x + threadIdx.x;
    int y = blockIdx.y;
    const int* rp = (y == 0) ? r0 : (y == 1) ? r1 : r2;
    const int* cp = (y == 0) ? c0 : (y == 1) ? c1 : c2;
    int* colp = (y == 0) ? col_adj : (y == 1) ? col_ent : col_rel;
    int Eg = (y == 0) ? E0 : (y == 1) ? E1 : E2;
    if (e >= Eg) return;
    int r = rp[e];
    int pos = atomicAdd(&cur3[(size_t)y * N + r], 1);
    colp[pos] = cp[e];
    if (y == 0) {
        eid_adj[pos] = e;
        row_adj[pos] = r;
        rel_attn_s[pos] = sp_val[e] * proj[sp_col[e]];
    }
}

__global__ void rel_proj_k(const float* __restrict__ rel_emb, const float* __restrict__ a_rel,
                           float* __restrict__ proj, int R) {
    int r = blockIdx.x * blockDim.x + threadIdx.x;
    if (r >= R) return;
    float s = 0.0f;
    #pragma unroll 4
    for (int f = 0; f < NODE_F; ++f) s += rel_emb[(size_t)r * NODE_F + f] * a_rel[f];
    proj[r] = s;
}

// per-edge attention logit (flat, all lanes active, latency fully hidden by TLP)
__global__ void edge_att_k(const int* __restrict__ row_s, const int* __restrict__ col_s,
                           const float* __restrict__ rel_attn_s,
                           const float* __restrict__ a_s, const float* __restrict__ a_n,
                           float* __restrict__ att_raw, int E) {
    int p = blockIdx.x * blockDim.x + threadIdx.x;
    if (p >= E) return;
    float v = rel_attn_s[p] + a_s[row_s[p]] + a_n[col_s[p]];
    att_raw[p] = v >= 0.0f ? v : 0.2f * v;   // leaky relu
}

// ================= fused feature kernels =================

// one wave per node, split-wave: lanes 0-31 gather ent rows (float4, 512B/row),
// lanes 32-63 gather rel rows, concurrently. One 1KB wave write; fused relu +
// a_s/a_n dots in-register.
__global__ void meanagg_fused_k(const int* __restrict__ st_ent, const int* __restrict__ dg_ent,
                                const int* __restrict__ col_ent,
                                const int* __restrict__ st_rel, const int* __restrict__ dg_rel,
                                const int* __restrict__ col_rel,
                                const float* __restrict__ ent_emb, const float* __restrict__ rel_emb,
                                const float* __restrict__ a_self, const float* __restrict__ a_neigh,
                                float* __restrict__ out,
                                float* __restrict__ a_s_out, float* __restrict__ a_n_out, int N) {
    int n = blockIdx.x * (blockDim.x >> 6) + (threadIdx.x >> 6);
    int lane = threadIdx.x & 63;
    if (n >= N) return;

    int half = lane >> 5;              // 0: ent (out cols 0..127), 1: rel (cols 128..255)
    int hl = lane & 31;
    int s  = half ? st_rel[n] : st_ent[n];
    int dg = half ? dg_rel[n] : dg_ent[n];
    const int* colp = half ? col_rel : col_ent;
    const float* emb = half ? rel_emb : ent_emb;

    float4 acc = {0.0f, 0.0f, 0.0f, 0.0f};
    for (int p = 0; p < dg; ++p) {     // halves diverge; exec mask handles
        int c = colp[s + p];
        float4 v = reinterpret_cast<const float4*>(&emb[(size_t)c * NODE_F])[hl];
        acc.x += v.x; acc.y += v.y; acc.z += v.z; acc.w += v.w;
    }
    if (dg > 0) {
        float w = 1.0f / (float)dg;
        acc.x *= w; acc.y *= w; acc.z *= w; acc.w *= w;
    }
    acc.x = acc.x > 0.0f ? acc.x : 0.0f;
    acc.y = acc.y > 0.0f ? acc.y : 0.0f;
    acc.z = acc.z > 0.0f ? acc.z : 0.0f;
    acc.w = acc.w > 0.0f ? acc.w : 0.0f;

    reinterpret_cast<float4*>(&out[(size_t)n * LDO])[lane] = acc;   // 1KB wave store

    float4 s4 = reinterpret_cast<const float4*>(a_self)[lane];
    float4 n4 = reinterpret_cast<const float4*>(a_neigh)[lane];
    float ds = acc.x * s4.x + acc.y * s4.y + acc.z * s4.z + acc.w * s4.w;
    float dn = acc.x * n4.x + acc.y * n4.y + acc.z * n4.z + acc.w * n4.w;
    #pragma unroll
    for (int o = 32; o > 0; o >>= 1) {
        ds += __shfl_xor(ds, o);
        dn += __shfl_xor(dn, o);
    }
    if (lane == 0) { a_s_out[n] = ds; a_n_out[n] = dn; }
}

// one wave per node: softmax from precomputed att_raw + weighted gather + relu
// + optional next-depth a_s/a_n + optional att scatter. NT: nontemporal stores.
template <int NT>
__global__ void attn_agg_slim_k(const int* __restrict__ st, const int* __restrict__ dg,
                                const int* __restrict__ col_s, const int* __restrict__ eid_s,
                                const float* __restrict__ att_raw,
                                const float* __restrict__ a_self, const float* __restrict__ a_neigh,
                                float* __restrict__ a_s_out, float* __restrict__ a_n_out,
                                float* __restrict__ out, int src, int dst,
                                float* __restrict__ att_out, int N) {
    int n = blockIdx.x * (blockDim.x >> 6) + (threadIdx.x >> 6);
    int lane = threadIdx.x & 63;
    if (n >= N) return;
    int s = st[n];
    int deg = dg[n];
    float4 acc = {0.0f, 0.0f, 0.0f, 0.0f};

    if (deg > 0) {
        if (deg <= 64) {
            float myv = NEG_INF;
            int mycol = 0;
            if (lane < deg) {
                mycol = col_s[s + lane];
                myv = att_raw[s + lane];
            }
            float m = myv;
            #pragma unroll
            for (int o = 32; o > 0; o >>= 1) {
                float x = __shfl_xor(m, o);
                m = x > m ? x : m;
            }
            float ex = (lane < deg) ? __expf(myv - m) : 0.0f;
            float ssum = ex;
            #pragma unroll
            for (int o = 32; o > 0; o >>= 1) ssum += __shfl_xor(ssum, o);
            float myatt = ex / ssum;
            if (att_out && lane < deg) {
                if (NT) __builtin_nontemporal_store(myatt, &att_out[eid_s[s + lane]]);
                else    att_out[eid_s[s + lane]] = myatt;
            }
            for (int p = 0; p < deg; ++p) {
                float a = __shfl(myatt, p);
                int c = __shfl(mycol, p);
                float4 v = reinterpret_cast<const float4*>(&out[(size_t)c * LDO + src])[lane];
                acc.x += a * v.x; acc.y += a * v.y; acc.z += a * v.z; acc.w += a * v.w;
            }
        } else {  // rare fallback: deg > 64
            float m = NEG_INF;
            for (int p = s + lane; p < s + deg; p += 64) {
                float v = att_raw[p];
                m = v > m ? v : m;
            }
            #pragma unroll
            for (int o = 32; o > 0; o >>= 1) {
                float x = __shfl_xor(m, o);
                m = x > m ? x : m;
            }
            float ssum = 0.0f;
            for (int p = s + lane; p < s + deg; p += 64) ssum += __expf(att_raw[p] - m);
            #pragma unroll
            for (int o = 32; o > 0; o >>= 1) ssum += __shfl_xor(ssum, o);
            float inv = 1.0f / ssum;
            for (int p = s; p < s + deg; ++p) {
                int c = col_s[p];
                float a = __expf(att_raw[p] - m) * inv;
                if (att_out && lane == 0) att_out[eid_s[p]] = a;
                float4 fv = reinterpret_cast<const float4*>(&out[(size_t)c * LDO + src])[lane];
                acc.x += a * fv.x; acc.y += a * fv.y; acc.z += a * fv.z; acc.w += a * fv.w;
            }
        }
    }

    acc.x = acc.x > 0.0f ? acc.x : 0.0f;
    acc.y = acc.y > 0.0f ? acc.y : 0.0f;
    acc.z = acc.z > 0.0f ? acc.z : 0.0f;
    acc.w = acc.w > 0.0f ? acc.w : 0.0f;
    float* dstp = &out[(size_t)n * LDO + dst] + (size_t)lane * 4;
    if (NT) {
        vf4 v; v.x = acc.x; v.y = acc.y; v.z = acc.z; v.w = acc.w;
        __builtin_nontemporal_store(v, reinterpret_cast<vf4*>(dstp));
    } else {
        *reinterpret_cast<float4*>(dstp) = acc;
    }

    if (a_s_out) {
        float4 s4 = reinterpret_cast<const float4*>(a_self)[lane];
        float4 n4 = reinterpret_cast<const float4*>(a_neigh)[lane];
        float ds = acc.x * s4.x + acc.y * s4.y + acc.z * s4.z + acc.w * s4.w;
        float dn = acc.x * n4.x + acc.y * n4.y + acc.z * n4.z + acc.w * n4.w;
        #pragma unroll
        for (int o = 32; o > 0; o >>= 1) {
            ds += __shfl_xor(ds, o);
            dn += __shfl_xor(dn, o);
        }
        if (lane == 0) { a_s_out[n] = ds; a_n_out[n] = dn; }
    }
}

// ================= launch =================

extern "C" void kernel_launch(void* const* d_in, const int* in_sizes, int n_in,
                              void* d_out, int out_size, void* d_ws, size_t ws_size,
                              hipStream_t stream) {
    const float* ent_emb = (const float*)d_in[0];
    const float* rel_emb = (const float*)d_in[1];
    const float* a_self  = (const float*)d_in[2];
    const float* a_neigh = (const float*)d_in[3];
    const float* a_rel   = (const float*)d_in[4];
    const float* sp_val  = (const float*)d_in[5];
    const int*   adj_row = (const int*)d_in[6];
    const int*   adj_col = (const int*)d_in[7];
    const int*   sp_col  = (const int*)d_in[9];
    const int*   rel_row = (const int*)d_in[10];
    const int*   rel_col = (const int*)d_in[11];
    const int*   ent_row = (const int*)d_in[12];
    const int*   ent_col = (const int*)d_in[13];

    const int N  = in_sizes[0] / NODE_F;
    const int R  = in_sizes[1] / NODE_F;
    const int E  = in_sizes[5];
    const int ER = in_sizes[10];
    const int EE = in_sizes[12];

    float* out = (float*)d_out;
    float* att_out = out + (size_t)N * LDO;

    const int TB = 256;
    const int nb = (N + 255) / 256;            // <= 512
    int maxE = E > EE ? E : EE; if (ER > maxE) maxE = ER;

    // ---- workspace ----
    char* w = (char*)d_ws;
    int* deg3    = (int*)w;  w += (size_t)3 * N * 4;
    int* rs3     = (int*)w;  w += (size_t)3 * N * 4;
    int* cur3    = (int*)w;  w += (size_t)3 * N * 4;
    int* bs3     = (int*)w;  w += (size_t)3 * 512 * 4;
    int* col_adj = (int*)w;  w += (size_t)E * 4;
    int* eid_adj = (int*)w;  w += (size_t)E * 4;
    int* row_adj = (int*)w;  w += (size_t)E * 4;
    int* col_ent = (int*)w;  w += (size_t)EE * 4;
    int* col_rel = (int*)w;  w += (size_t)ER * 4;
    float* rel_attn_s = (float*)w;  w += (size_t)E * 4;
    float* att_raw    = (float*)w;  w += (size_t)E * 4;
    float* proj       = (float*)w;  w += (size_t)R * 4;
    float* a_s0       = (float*)w;  w += (size_t)N * 4;
    float* a_n0       = (float*)w;  w += (size_t)N * 4;
    float* a_s1       = (float*)w;  w += (size_t)N * 4;
    float* a_n1       = (float*)w;  w += (size_t)N * 4;

    int* st_adj = rs3;          int* dg_adj = deg3;
    int* st_ent = rs3 + N;      int* dg_ent = deg3 + N;
    int* st_rel = rs3 + 2 * N;  int* dg_rel = deg3 + 2 * N;

    const int gE = (E + TB - 1) / TB;

    // ---- rel projection (tiny; needed by scatter3) ----
    rel_proj_k<<<(R + TB - 1) / TB, TB, 0, stream>>>(rel_emb, a_rel, proj, R);

    // ---- CSR build: count -> scan (monotone) -> scatter(+rel_attn fused) ----
    hipMemsetAsync(deg3, 0, (size_t)3 * N * sizeof(int), stream);
    {
        dim3 g((maxE + TB - 1) / TB, 3);
        count3_k<<<g, TB, 0, stream>>>(adj_row, ent_row, rel_row, E, EE, ER, deg3, N);
    }
    {
        dim3 g(nb, 3);
        blocksum3_k<<<g, 256, 0, stream>>>(deg3, bs3, N);
        scanbsum3_k<<<3, 512, 0, stream>>>(bs3, nb);
        scandeg3_k<<<g, 256, 0, stream>>>(deg3, bs3, rs3, cur3, N);
    }
    {
        dim3 g((maxE + TB - 1) / TB, 3);
        scatter3_k<<<g, TB, 0, stream>>>(adj_row, adj_col, ent_row, ent_col, rel_row, rel_col,
                                         E, EE, ER, cur3, col_adj, eid_adj, row_adj,
                                         col_ent, col_rel, sp_val, sp_col, proj, rel_attn_s, N);
    }

    // ---- initial features + depth-1 a_s/a_n (split-wave float4 gather) ----
    meanagg_fused_k<<<(N + 3) / 4, 256, 0, stream>>>(st_ent, dg_ent, col_ent,
                                                     st_rel, dg_rel, col_rel,
                                                     ent_emb, rel_emb, a_self, a_neigh,
                                                     out, a_s0, a_n0, N);

    // ---- depth 1 ----
    edge_att_k<<<gE, TB, 0, stream>>>(row_adj, col_adj, rel_attn_s, a_s0, a_n0, att_raw, E);
    attn_agg_slim_k<0><<<(N + 3) / 4, 256, 0, stream>>>(st_adj, dg_adj, col_adj, eid_adj,
                                                        att_raw, a_self, a_neigh, a_s1, a_n1,
                                                        out, 0, ENT_F, nullptr, N);

    // ---- depth 2 (nontemporal final stores) ----
    edge_att_k<<<gE, TB, 0, stream>>>(row_adj, col_adj, rel_attn_s, a_s1, a_n1, att_raw, E);
    attn_agg_slim_k<1><<<(N + 3) / 4, 256, 0, stream>>>(st_adj, dg_adj, col_adj, eid_adj,
                                                        att_raw, nullptr, nullptr, nullptr, nullptr,
                                                        out, ENT_F, 2 * ENT_F, att_out, N);
}

// Round 10
// 324.777 us; speedup vs baseline: 1.3198x; 1.0120x over previous
//
#include <hip/hip_runtime.h>

#define NODE_F 128
#define ENT_F  256
#define LDO    768   // out row stride: ENT_F * (DEPTH+1)
#define NEG_INF -3.4e38f

typedef float vf4 __attribute__((ext_vector_type(4)));

// ================= CSR build =================
// count3: blockIdx.y = 0:adj, 1:ent, 2:rel degree count; 3: rel_proj (fused)

__global__ void count3_k(const int* __restrict__ r0, const int* __restrict__ r1,
                         const int* __restrict__ r2, int E0, int E1, int E2,
                         int* __restrict__ deg3, int N,
                         const float* __restrict__ rel_emb, const float* __restrict__ a_rel,
                         float* __restrict__ proj, int R) {
    int i = blockIdx.x * blockDim.x + threadIdx.x;
    int y = blockIdx.y;
    if (y == 3) {                       // fused rel_proj
        if (i < R) {
            float s = 0.0f;
            #pragma unroll 4
            for (int f = 0; f < NODE_F; ++f) s += rel_emb[(size_t)i * NODE_F + f] * a_rel[f];
            proj[i] = s;
        }
        return;
    }
    const int* rp = (y == 0) ? r0 : (y == 1) ? r1 : r2;
    int Eg = (y == 0) ? E0 : (y == 1) ? E1 : E2;
    if (i < Eg) atomicAdd(&deg3[(size_t)y * N + rp[i]], 1);
}

// per-256-chunk sums of deg (raw, unscanned)
__global__ void blocksum3_k(const int* __restrict__ deg3, int* __restrict__ bs3, int N) {
    __shared__ int s[256];
    int y = blockIdx.y;
    int i = blockIdx.x * 256 + threadIdx.x;
    s[threadIdx.x] = (i < N) ? deg3[(size_t)y * N + i] : 0;
    __syncthreads();
    for (int o = 128; o > 0; o >>= 1) {
        if (threadIdx.x < o) s[threadIdx.x] += s[threadIdx.x + o];
        __syncthreads();
    }
    if (threadIdx.x == 0) bs3[y * 512 + blockIdx.x] = s[0];
}

// per-chunk scan with self-computed chunk prefix (reads raw bs3 of all prior chunks)
// -> row_start (rs3) and scatter cursor (cur3). Kills the serial scanbsum dispatch.
__global__ void scandeg3_k(const int* __restrict__ deg3, const int* __restrict__ bs3,
                           int* __restrict__ rs3, int* __restrict__ cur3, int N) {
    __shared__ int s[256];
    __shared__ int basep;
    int y = blockIdx.y;
    int i = blockIdx.x * 256 + threadIdx.x;

    // chunk prefix: sum bs3[y*512 + 0 .. blockIdx.x-1]  (nb <= 512)
    int pv = 0;
    if ((int)threadIdx.x < blockIdx.x) pv = bs3[y * 512 + threadIdx.x];
    if ((int)threadIdx.x + 256 < blockIdx.x) pv += bs3[y * 512 + threadIdx.x + 256];
    s[threadIdx.x] = pv;
    __syncthreads();
    for (int o = 128; o > 0; o >>= 1) {
        if (threadIdx.x < o) s[threadIdx.x] += s[threadIdx.x + o];
        __syncthreads();
    }
    if (threadIdx.x == 0) basep = s[0];
    __syncthreads();
    int base = basep;
    __syncthreads();                    // s[] about to be reused

    // local exclusive scan of this chunk's degrees
    int v = (i < N) ? deg3[(size_t)y * N + i] : 0;
    s[threadIdx.x] = v;
    __syncthreads();
    for (int o = 1; o < 256; o <<= 1) {
        int t = (threadIdx.x >= o) ? s[threadIdx.x - o] : 0;
        __syncthreads();
        s[threadIdx.x] += t;
        __syncthreads();
    }
    if (i < N) {
        int rs = base + s[threadIdx.x] - v;
        rs3[(size_t)y * N + i] = rs;
        cur3[(size_t)y * N + i] = rs;
    }
}

// scatter; for adj also store row id, eid, and fused rel_attn (sp_row == arange(E)).
__global__ void scatter3_k(const int* __restrict__ r0, const int* __restrict__ c0,
                           const int* __restrict__ r1, const int* __restrict__ c1,
                           const int* __restrict__ r2, const int* __restrict__ c2,
                           int E0, int E1, int E2, int* __restrict__ cur3,
                           int* __restrict__ col_adj, int* __restrict__ eid_adj,
                           int* __restrict__ row_adj,
                           int* __restrict__ col_ent, int* __restrict__ col_rel,
                           const float* __restrict__ sp_val, const int* __restrict__ sp_col,
                           const float* __restrict__ proj, float* __restrict__ rel_attn_s,
                           int N) {
    int e = blockIdx.x * blockDim.x + threadIdx.x;
    int y = blockIdx.y;
    const int* rp = (y == 0) ? r0 : (y == 1) ? r1 : r2;
    const int* cp = (y == 0) ? c0 : (y == 1) ? c1 : c2;
    int* colp = (y == 0) ? col_adj : (y == 1) ? col_ent : col_rel;
    int Eg = (y == 0) ? E0 : (y == 1) ? E1 : E2;
    if (e >= Eg) return;
    int r = rp[e];
    int pos = atomicAdd(&cur3[(size_t)y * N + r], 1);
    colp[pos] = cp[e];
    if (y == 0) {
        eid_adj[pos] = e;
        row_adj[pos] = r;
        rel_attn_s[pos] = sp_val[e] * proj[sp_col[e]];
    }
}

// per-edge attention logit (flat, all lanes active, latency fully hidden by TLP)
__global__ void edge_att_k(const int* __restrict__ row_s, const int* __restrict__ col_s,
                           const float* __restrict__ rel_attn_s,
                           const float* __restrict__ a_s, const float* __restrict__ a_n,
                           float* __restrict__ att_raw, int E) {
    int p = blockIdx.x * blockDim.x + threadIdx.x;
    if (p >= E) return;
    float v = rel_attn_s[p] + a_s[row_s[p]] + a_n[col_s[p]];
    att_raw[p] = v >= 0.0f ? v : 0.2f * v;   // leaky relu
}

// ================= fused feature kernels =================

// one wave per node, split-wave: lanes 0-31 gather ent rows (float4, 512B/row),
// lanes 32-63 gather rel rows, concurrently. One 1KB wave write; fused relu +
// a_s/a_n dots in-register.
__global__ void meanagg_fused_k(const int* __restrict__ st_ent, const int* __restrict__ dg_ent,
                                const int* __restrict__ col_ent,
                                const int* __restrict__ st_rel, const int* __restrict__ dg_rel,
                                const int* __restrict__ col_rel,
                                const float* __restrict__ ent_emb, const float* __restrict__ rel_emb,
                                const float* __restrict__ a_self, const float* __restrict__ a_neigh,
                                float* __restrict__ out,
                                float* __restrict__ a_s_out, float* __restrict__ a_n_out, int N) {
    int n = blockIdx.x * (blockDim.x >> 6) + (threadIdx.x >> 6);
    int lane = threadIdx.x & 63;
    if (n >= N) return;

    int half = lane >> 5;              // 0: ent (out cols 0..127), 1: rel (cols 128..255)
    int hl = lane & 31;
    int s  = half ? st_rel[n] : st_ent[n];
    int dg = half ? dg_rel[n] : dg_ent[n];
    const int* colp = half ? col_rel : col_ent;
    const float* emb = half ? rel_emb : ent_emb;

    float4 acc = {0.0f, 0.0f, 0.0f, 0.0f};
    for (int p = 0; p < dg; ++p) {     // halves diverge; exec mask handles
        int c = colp[s + p];
        float4 v = reinterpret_cast<const float4*>(&emb[(size_t)c * NODE_F])[hl];
        acc.x += v.x; acc.y += v.y; acc.z += v.z; acc.w += v.w;
    }
    if (dg > 0) {
        float w = 1.0f / (float)dg;
        acc.x *= w; acc.y *= w; acc.z *= w; acc.w *= w;
    }
    acc.x = acc.x > 0.0f ? acc.x : 0.0f;
    acc.y = acc.y > 0.0f ? acc.y : 0.0f;
    acc.z = acc.z > 0.0f ? acc.z : 0.0f;
    acc.w = acc.w > 0.0f ? acc.w : 0.0f;

    reinterpret_cast<float4*>(&out[(size_t)n * LDO])[lane] = acc;   // 1KB wave store

    float4 s4 = reinterpret_cast<const float4*>(a_self)[lane];
    float4 n4 = reinterpret_cast<const float4*>(a_neigh)[lane];
    float ds = acc.x * s4.x + acc.y * s4.y + acc.z * s4.z + acc.w * s4.w;
    float dn = acc.x * n4.x + acc.y * n4.y + acc.z * n4.z + acc.w * n4.w;
    #pragma unroll
    for (int o = 32; o > 0; o >>= 1) {
        ds += __shfl_xor(ds, o);
        dn += __shfl_xor(dn, o);
    }
    if (lane == 0) { a_s_out[n] = ds; a_n_out[n] = dn; }
}

// one wave per node: softmax from precomputed att_raw + weighted gather + relu
// + optional next-depth a_s/a_n + optional att scatter. NT: nontemporal stores.
template <int NT>
__global__ void attn_agg_slim_k(const int* __restrict__ st, const int* __restrict__ dg,
                                const int* __restrict__ col_s, const int* __restrict__ eid_s,
                                const float* __restrict__ att_raw,
                                const float* __restrict__ a_self, const float* __restrict__ a_neigh,
                                float* __restrict__ a_s_out, float* __restrict__ a_n_out,
                                float* __restrict__ out, int src, int dst,
                                float* __restrict__ att_out, int N) {
    int n = blockIdx.x * (blockDim.x >> 6) + (threadIdx.x >> 6);
    int lane = threadIdx.x & 63;
    if (n >= N) return;
    int s = st[n];
    int deg = dg[n];
    float4 acc = {0.0f, 0.0f, 0.0f, 0.0f};

    if (deg > 0) {
        if (deg <= 64) {
            float myv = NEG_INF;
            int mycol = 0;
            if (lane < deg) {
                mycol = col_s[s + lane];
                myv = att_raw[s + lane];
            }
            float m = myv;
            #pragma unroll
            for (int o = 32; o > 0; o >>= 1) {
                float x = __shfl_xor(m, o);
                m = x > m ? x : m;
            }
            float ex = (lane < deg) ? __expf(myv - m) : 0.0f;
            float ssum = ex;
            #pragma unroll
            for (int o = 32; o > 0; o >>= 1) ssum += __shfl_xor(ssum, o);
            float myatt = ex / ssum;
            if (att_out && lane < deg) {
                if (NT) __builtin_nontemporal_store(myatt, &att_out[eid_s[s + lane]]);
                else    att_out[eid_s[s + lane]] = myatt;
            }
            for (int p = 0; p < deg; ++p) {
                float a = __shfl(myatt, p);
                int c = __shfl(mycol, p);
                float4 v = reinterpret_cast<const float4*>(&out[(size_t)c * LDO + src])[lane];
                acc.x += a * v.x; acc.y += a * v.y; acc.z += a * v.z; acc.w += a * v.w;
            }
        } else {  // rare fallback: deg > 64
            float m = NEG_INF;
            for (int p = s + lane; p < s + deg; p += 64) {
                float v = att_raw[p];
                m = v > m ? v : m;
            }
            #pragma unroll
            for (int o = 32; o > 0; o >>= 1) {
                float x = __shfl_xor(m, o);
                m = x > m ? x : m;
            }
            float ssum = 0.0f;
            for (int p = s + lane; p < s + deg; p += 64) ssum += __expf(att_raw[p] - m);
            #pragma unroll
            for (int o = 32; o > 0; o >>= 1) ssum += __shfl_xor(ssum, o);
            float inv = 1.0f / ssum;
            for (int p = s; p < s + deg; ++p) {
                int c = col_s[p];
                float a = __expf(att_raw[p] - m) * inv;
                if (att_out && lane == 0) att_out[eid_s[p]] = a;
                float4 fv = reinterpret_cast<const float4*>(&out[(size_t)c * LDO + src])[lane];
                acc.x += a * fv.x; acc.y += a * fv.y; acc.z += a * fv.z; acc.w += a * fv.w;
            }
        }
    }

    acc.x = acc.x > 0.0f ? acc.x : 0.0f;
    acc.y = acc.y > 0.0f ? acc.y : 0.0f;
    acc.z = acc.z > 0.0f ? acc.z : 0.0f;
    acc.w = acc.w > 0.0f ? acc.w : 0.0f;
    float* dstp = &out[(size_t)n * LDO + dst] + (size_t)lane * 4;
    if (NT) {
        vf4 v; v.x = acc.x; v.y = acc.y; v.z = acc.z; v.w = acc.w;
        __builtin_nontemporal_store(v, reinterpret_cast<vf4*>(dstp));
    } else {
        *reinterpret_cast<float4*>(dstp) = acc;
    }

    if (a_s_out) {
        float4 s4 = reinterpret_cast<const float4*>(a_self)[lane];
        float4 n4 = reinterpret_cast<const float4*>(a_neigh)[lane];
        float ds = acc.x * s4.x + acc.y * s4.y + acc.z * s4.z + acc.w * s4.w;
        float dn = acc.x * n4.x + acc.y * n4.y + acc.z * n4.z + acc.w * n4.w;
        #pragma unroll
        for (int o = 32; o > 0; o >>= 1) {
            ds += __shfl_xor(ds, o);
            dn += __shfl_xor(dn, o);
        }
        if (lane == 0) { a_s_out[n] = ds; a_n_out[n] = dn; }
    }
}

// ================= launch =================

extern "C" void kernel_launch(void* const* d_in, const int* in_sizes, int n_in,
                              void* d_out, int out_size, void* d_ws, size_t ws_size,
                              hipStream_t stream) {
    const float* ent_emb = (const float*)d_in[0];
    const float* rel_emb = (const float*)d_in[1];
    const float* a_self  = (const float*)d_in[2];
    const float* a_neigh = (const float*)d_in[3];
    const float* a_rel   = (const float*)d_in[4];
    const float* sp_val  = (const float*)d_in[5];
    const int*   adj_row = (const int*)d_in[6];
    const int*   adj_col = (const int*)d_in[7];
    const int*   sp_col  = (const int*)d_in[9];
    const int*   rel_row = (const int*)d_in[10];
    const int*   rel_col = (const int*)d_in[11];
    const int*   ent_row = (const int*)d_in[12];
    const int*   ent_col = (const int*)d_in[13];

    const int N  = in_sizes[0] / NODE_F;
    const int R  = in_sizes[1] / NODE_F;
    const int E  = in_sizes[5];
    const int ER = in_sizes[10];
    const int EE = in_sizes[12];

    float* out = (float*)d_out;
    float* att_out = out + (size_t)N * LDO;

    const int TB = 256;
    const int nb = (N + 255) / 256;            // <= 512
    int maxE = E > EE ? E : EE; if (ER > maxE) maxE = ER;

    // ---- workspace ----
    char* w = (char*)d_ws;
    int* deg3    = (int*)w;  w += (size_t)3 * N * 4;
    int* rs3     = (int*)w;  w += (size_t)3 * N * 4;
    int* cur3    = (int*)w;  w += (size_t)3 * N * 4;
    int* bs3     = (int*)w;  w += (size_t)3 * 512 * 4;
    int* col_adj = (int*)w;  w += (size_t)E * 4;
    int* eid_adj = (int*)w;  w += (size_t)E * 4;
    int* row_adj = (int*)w;  w += (size_t)E * 4;
    int* col_ent = (int*)w;  w += (size_t)EE * 4;
    int* col_rel = (int*)w;  w += (size_t)ER * 4;
    float* rel_attn_s = (float*)w;  w += (size_t)E * 4;
    float* att_raw    = (float*)w;  w += (size_t)E * 4;
    float* proj       = (float*)w;  w += (size_t)R * 4;
    float* a_s0       = (float*)w;  w += (size_t)N * 4;
    float* a_n0       = (float*)w;  w += (size_t)N * 4;
    float* a_s1       = (float*)w;  w += (size_t)N * 4;
    float* a_n1       = (float*)w;  w += (size_t)N * 4;

    int* st_adj = rs3;          int* dg_adj = deg3;
    int* st_ent = rs3 + N;      int* dg_ent = deg3 + N;
    int* st_rel = rs3 + 2 * N;  int* dg_rel = deg3 + 2 * N;

    const int gE = (E + TB - 1) / TB;

    // ---- CSR build: count(+rel_proj fused) -> blocksum -> scandeg(self-prefix) -> scatter ----
    hipMemsetAsync(deg3, 0, (size_t)3 * N * sizeof(int), stream);
    {
        dim3 g((maxE + TB - 1) / TB, 4);      // y==3: rel_proj
        count3_k<<<g, TB, 0, stream>>>(adj_row, ent_row, rel_row, E, EE, ER, deg3, N,
                                       rel_emb, a_rel, proj, R);
    }
    {
        dim3 g(nb, 3);
        blocksum3_k<<<g, 256, 0, stream>>>(deg3, bs3, N);
        scandeg3_k<<<g, 256, 0, stream>>>(deg3, bs3, rs3, cur3, N);
    }
    {
        dim3 g((maxE + TB - 1) / TB, 3);
        scatter3_k<<<g, TB, 0, stream>>>(adj_row, adj_col, ent_row, ent_col, rel_row, rel_col,
                                         E, EE, ER, cur3, col_adj, eid_adj, row_adj,
                                         col_ent, col_rel, sp_val, sp_col, proj, rel_attn_s, N);
    }

    // ---- initial features + depth-1 a_s/a_n (split-wave float4 gather) ----
    meanagg_fused_k<<<(N + 3) / 4, 256, 0, stream>>>(st_ent, dg_ent, col_ent,
                                                     st_rel, dg_rel, col_rel,
                                                     ent_emb, rel_emb, a_self, a_neigh,
                                                     out, a_s0, a_n0, N);

    // ---- depth 1 ----
    edge_att_k<<<gE, TB, 0, stream>>>(row_adj, col_adj, rel_attn_s, a_s0, a_n0, att_raw, E);
    attn_agg_slim_k<0><<<(N + 3) / 4, 256, 0, stream>>>(st_adj, dg_adj, col_adj, eid_adj,
                                                        att_raw, a_self, a_neigh, a_s1, a_n1,
                                                        out, 0, ENT_F, nullptr, N);

    // ---- depth 2 (nontemporal final stores) ----
    edge_att_k<<<gE, TB, 0, stream>>>(row_adj, col_adj, rel_attn_s, a_s1, a_n1, att_raw, E);
    attn_agg_slim_k<1><<<(N + 3) / 4, 256, 0, stream>>>(st_adj, dg_adj, col_adj, eid_adj,
                                                        att_raw, nullptr, nullptr, nullptr, nullptr,
                                                        out, ENT_F, 2 * ENT_F, att_out, N);
}